// Round 4
// baseline (206.075 us; speedup 1.0000x reference)
//
#include <hip/hip_runtime.h>
#include <math.h>

#define BB 32
#define TT 256
#define DD 1024
#define NNODES 2048
#define EE 65536
#define LN_EPS 1e-5f

typedef __attribute__((ext_vector_type(8))) short shortx8;
typedef __attribute__((ext_vector_type(4))) float floatx4;
typedef __attribute__((ext_vector_type(8))) unsigned short ushortx8;

__device__ __forceinline__ float gelu_fast(float x) {
    // tanh-approx gelu: x - x/(1+exp2(x*(2.302118 + 0.102945*x^2)))
    float x2 = x * x;
    float z = x * fmaf(0.10294456f, x2, 2.30211786f);
    float e = __builtin_amdgcn_exp2f(z);
    float r = __builtin_amdgcn_rcpf(1.0f + e);
    return fmaf(-x, r, x);
}

__device__ __forceinline__ unsigned short f32_to_bf16(float f) {
    unsigned u = __float_as_uint(f);
    unsigned r = (u + 0x7FFF + ((u >> 16) & 1)) >> 16;
    return (unsigned short)r;
}

__device__ __forceinline__ float bf16_to_f32(unsigned short h) {
    return __uint_as_float(((unsigned)h) << 16);
}

__device__ __forceinline__ void load_lds16(const void* g, void* l) {
    __builtin_amdgcn_global_load_lds(
        (const __attribute__((address_space(1))) void*)g,
        (__attribute__((address_space(3))) void*)l, 16, 0, 0);
}

// Zero d_out (energy+forces) and the sort histogram bins.
__global__ void zero_out_kernel(float* __restrict__ out, int n,
                                int* __restrict__ bins) {
    int i = blockIdx.x * blockDim.x + threadIdx.x;
    if (i < n) out[i] = 0.0f;
    if (i < NNODES) bins[i] = 0;
}

// LayerNorm of x[:,0,:] -> hnorm (32 x 1024). grid=32, block=256.
__global__ void ln_kernel(const float* __restrict__ x, const float* __restrict__ g,
                          const float* __restrict__ bta, float* __restrict__ hnorm) {
    __shared__ float red[256];
    int b = blockIdx.x;
    int t = threadIdx.x;
    const float* row = x + (size_t)b * TT * DD;
    float v[4];
    float s = 0.0f;
    #pragma unroll
    for (int j = 0; j < 4; ++j) { v[j] = row[t + j * 256]; s += v[j]; }
    red[t] = s; __syncthreads();
    for (int off = 128; off > 0; off >>= 1) {
        if (t < off) red[t] += red[t + off];
        __syncthreads();
    }
    float mu = red[0] * (1.0f / DD);
    __syncthreads();
    float sq = 0.0f;
    #pragma unroll
    for (int j = 0; j < 4; ++j) { float d = v[j] - mu; sq += d * d; }
    red[t] = sq; __syncthreads();
    for (int off = 128; off > 0; off >>= 1) {
        if (t < off) red[t] += red[t + off];
        __syncthreads();
    }
    float rstd = rsqrtf(red[0] * (1.0f / DD) + LN_EPS);
    #pragma unroll
    for (int j = 0; j < 4; ++j) {
        int d = t + j * 256;
        hnorm[b * DD + d] = (v[j] - mu) * rstd * g[d] + bta[d];
    }
}

// Split-K/row partial GEMM: He[ks][r0+r][col] = sum_{k chunk} h[r][k]*We1[k][col]
// grid (4 col-tiles of 256, 8 k-splits of 128, 2 row-groups of 16), block 256.
__global__ __launch_bounds__(256) void energy1_kernel(
    const float* __restrict__ hnorm, const float* __restrict__ We1,
    float* __restrict__ He) {
    __shared__ float hs[128 * 16];  // [k][r], broadcast reads
    int t = threadIdx.x;
    int col = blockIdx.x * 256 + t;
    int k0 = blockIdx.y * 128;
    int r0 = blockIdx.z * 16;
    for (int idx = t; idx < 128 * 16; idx += 256) {
        int r = idx & 15, k = idx >> 4;
        hs[idx] = hnorm[(size_t)(r0 + r) * DD + k0 + k];
    }
    __syncthreads();
    float acc[16];
    #pragma unroll
    for (int r = 0; r < 16; ++r) acc[r] = 0.0f;
    #pragma unroll 4
    for (int k = 0; k < 128; ++k) {
        float w = We1[(size_t)(k0 + k) * DD + col];
        const float* hrow = hs + k * 16;
        #pragma unroll
        for (int j = 0; j < 4; ++j) {
            float4 h4 = *(const float4*)(hrow + j * 4);
            acc[j * 4 + 0] = fmaf(h4.x, w, acc[j * 4 + 0]);
            acc[j * 4 + 1] = fmaf(h4.y, w, acc[j * 4 + 1]);
            acc[j * 4 + 2] = fmaf(h4.z, w, acc[j * 4 + 2]);
            acc[j * 4 + 3] = fmaf(h4.w, w, acc[j * 4 + 3]);
        }
    }
    float* o = He + (size_t)blockIdx.y * 32 * DD;
    #pragma unroll
    for (int r = 0; r < 16; ++r) o[(size_t)(r0 + r) * DD + col] = acc[r];
}

// Epilogue: sum partials, gelu, dot We2. grid=32, block=256.
__global__ __launch_bounds__(256) void energy2_kernel(
    const float* __restrict__ He, const float* __restrict__ be1,
    const float* __restrict__ We2, const float* __restrict__ be2,
    float* __restrict__ out) {
    __shared__ float red[256];
    int b = blockIdx.x;
    int t = threadIdx.x;
    float p = 0.0f;
    #pragma unroll
    for (int j = 0; j < 4; ++j) {
        int c = t * 4 + j;
        float s = 0.0f;
        #pragma unroll
        for (int ks = 0; ks < 8; ++ks) s += He[(size_t)ks * 32 * DD + b * DD + c];
        s += be1[c];
        p += gelu_fast(s) * We2[c];
    }
    red[t] = p; __syncthreads();
    for (int off = 128; off > 0; off >>= 1) {
        if (t < off) red[t] += red[t + off];
        __syncthreads();
    }
    if (t == 0) out[b] = red[0] + be2[0];
}

// x node slices -> bf16 nodesB[2048][1024]. grid 2048, block 256 (4 els/thread).
__global__ void prep_nodes_kernel(const float* __restrict__ x,
                                  unsigned short* __restrict__ nodesB) {
    int idx4 = (blockIdx.x * 256 + threadIdx.x) * 4;
    int i = idx4 >> 10;
    int k = idx4 & 1023;
    const float* src = x + ((size_t)(i >> 6) * TT + 1 + (i & 63)) * DD + k;
    float4 v = *(const float4*)src;
    ushort4 o;
    o.x = f32_to_bf16(v.x); o.y = f32_to_bf16(v.y);
    o.z = f32_to_bf16(v.z); o.w = f32_to_bf16(v.w);
    *(ushort4*)&nodesB[idx4] = o;
}

// Wf1[2048][1024] fp32 -> Wf1T[half][n][k] bf16 (k within half, 1024).
// grid (32 n-tiles, 64 k-tiles), block 256 = (tx 32, ty 8). 32x32 tiles.
__global__ __launch_bounds__(256) void prep_wf1t_kernel(
    const float* __restrict__ Wf1, unsigned short* __restrict__ Wf1T) {
    __shared__ float tile[32][33];
    int tx = threadIdx.x & 31;
    int ty = threadIdx.x >> 5;
    int n0 = blockIdx.x * 32;
    int kg0 = blockIdx.y * 32;
    #pragma unroll
    for (int j = 0; j < 4; ++j) {
        int r = ty * 4 + j;
        tile[r][tx] = Wf1[(size_t)(kg0 + r) * DD + n0 + tx];
    }
    __syncthreads();
    int half = kg0 >> 10;
    int kk0 = kg0 & 1023;
    unsigned short* o = Wf1T + (size_t)half * DD * DD;
    #pragma unroll
    for (int j = 0; j < 4; ++j) {
        int rn = ty * 4 + j;
        o[(size_t)(n0 + rn) * DD + kk0 + tx] = f32_to_bf16(tile[tx][rn]);
    }
}

// ---- counting sort of edges by ei0 ----
// histogram: grid 256, block 256.
__global__ void hist_kernel(const int* __restrict__ edge_index,
                            int* __restrict__ bins) {
    int e = blockIdx.x * 256 + threadIdx.x;
    atomicAdd(&bins[edge_index[e]], 1);
}

// exclusive scan of 2048 bins -> cursor. 1 block, 256 threads, 8 bins each.
__global__ __launch_bounds__(256) void scan_kernel(const int* __restrict__ bins,
                                                   int* __restrict__ cursor) {
    __shared__ int part[256];
    int t = threadIdx.x;
    int local[8];
    int s = 0;
    #pragma unroll
    for (int j = 0; j < 8; ++j) { local[j] = s; s += bins[t * 8 + j]; }
    part[t] = s;
    __syncthreads();
    for (int d = 1; d < 256; d <<= 1) {
        int v = (t >= d) ? part[t - d] : 0;
        __syncthreads();
        part[t] += v;
        __syncthreads();
    }
    int base = (t == 0) ? 0 : part[t - 1];
    #pragma unroll
    for (int j = 0; j < 8; ++j) cursor[t * 8 + j] = base + local[j];
}

// scatter: grid 256, block 256. sorted[pos] = edge id, grouped by ei0.
__global__ void scatter_kernel(const int* __restrict__ edge_index,
                               int* __restrict__ cursor,
                               int* __restrict__ sorted) {
    int e = blockIdx.x * 256 + threadIdx.x;
    int i0 = edge_index[e];
    int pos = atomicAdd(&cursor[i0], 1);
    sorted[pos] = e;
}

// MFMA GEMM: P[half][i][n] = sum_k nodesB[i][k] * Wf1T[half][n][k]  (bf16 in/out)
// bf1 folded into half 0. Tile 128(n) x 64(i), BK=64.
// grid (8 n-tiles, 32 i-tiles, 2 halves) = 512 blocks -> 2 blocks/CU (R3 had 1/CU).
__global__ __launch_bounds__(256) void pgemm_mfma_kernel(
    const unsigned short* __restrict__ nodesB,
    const unsigned short* __restrict__ Wf1T, const float* __restrict__ bf1,
    unsigned short* __restrict__ P) {
    __shared__ unsigned short As[128 * 64];  // [n-row][k], XOR-swizzled chunks
    __shared__ unsigned short Bs[64 * 64];   // [i-row][k]
    int t = threadIdx.x;
    int w = t >> 6;
    int lane = t & 63;
    int quad = lane >> 4;
    int l16 = lane & 15;
    int wn = (w & 1) * 64;
    int wi = (w >> 1) * 32;
    int half = blockIdx.z;
    int n0 = blockIdx.x * 128;
    int i0 = blockIdx.y * 64;

    const unsigned short* Ag = Wf1T + (size_t)half * DD * DD;
    const unsigned short* Bg = nodesB;

    int sr = lane >> 3;
    int sc = (lane & 7) ^ sr;
    size_t aoff[4], boff[2];
    #pragma unroll
    for (int j = 0; j < 4; ++j)
        aoff[j] = (size_t)(n0 + w * 32 + j * 8 + sr) * DD + sc * 8;
    #pragma unroll
    for (int j = 0; j < 2; ++j)
        boff[j] = (size_t)(i0 + w * 16 + j * 8 + sr) * DD + sc * 8;

    floatx4 acc[4][2];
    #pragma unroll
    for (int a = 0; a < 4; ++a)
        #pragma unroll
        for (int b = 0; b < 2; ++b) {
            acc[a][b][0] = 0.f; acc[a][b][1] = 0.f;
            acc[a][b][2] = 0.f; acc[a][b][3] = 0.f;
        }

    for (int k0 = 0; k0 < DD; k0 += 64) {
        #pragma unroll
        for (int j = 0; j < 4; ++j)
            load_lds16(Ag + aoff[j] + k0, (void*)(As + (w * 32 + j * 8) * 64));
        #pragma unroll
        for (int j = 0; j < 2; ++j)
            load_lds16(Bg + boff[j] + k0, (void*)(Bs + (w * 16 + j * 8) * 64));
        __syncthreads();
        #pragma unroll
        for (int s = 0; s < 2; ++s) {
            shortx8 af[4], bfr[2];
            #pragma unroll
            for (int f = 0; f < 4; ++f) {
                int rn = wn + f * 16 + l16;
                af[f] = *(const shortx8*)&As[rn * 64 + ((((s << 2) | quad) ^ (rn & 7)) << 3)];
            }
            #pragma unroll
            for (int f = 0; f < 2; ++f) {
                int ri = wi + f * 16 + l16;
                bfr[f] = *(const shortx8*)&Bs[ri * 64 + ((((s << 2) | quad) ^ (ri & 7)) << 3)];
            }
            #pragma unroll
            for (int fa = 0; fa < 4; ++fa)
                #pragma unroll
                for (int fb = 0; fb < 2; ++fb)
                    acc[fa][fb] = __builtin_amdgcn_mfma_f32_16x16x32_bf16(
                        af[fa], bfr[fb], acc[fa][fb], 0, 0, 0);
        }
        __syncthreads();
    }

    unsigned short* Pout = P + (size_t)half * NNODES * DD;
    #pragma unroll
    for (int fa = 0; fa < 4; ++fa) {
        int n = n0 + wn + fa * 16 + quad * 4;
        float4 badd = make_float4(0.f, 0.f, 0.f, 0.f);
        if (half == 0) badd = *(const float4*)(bf1 + n);
        #pragma unroll
        for (int fb = 0; fb < 2; ++fb) {
            int i = i0 + wi + fb * 16 + l16;
            floatx4 v = acc[fa][fb];
            ushort4 o;
            o.x = f32_to_bf16(v[0] + badd.x);
            o.y = f32_to_bf16(v[1] + badd.y);
            o.z = f32_to_bf16(v[2] + badd.z);
            o.w = f32_to_bf16(v[3] + badd.w);
            *(ushort4*)&Pout[(size_t)i * DD + n] = o;
        }
    }
}

// Sorted edge kernel: wave per 8 consecutive sorted edges (grouped by i0).
// p0 row cached in 16 VGPRs per group; force accumulated in regs, one
// atomicAdd triple per group-chunk. grid 2048 blocks x 256 (8192 waves).
__global__ __launch_bounds__(256) void edge_sorted_kernel(
    const unsigned short* __restrict__ P, const int* __restrict__ sorted,
    const int* __restrict__ edge_index, const float* __restrict__ evec,
    const float* __restrict__ edist, const float* __restrict__ Wf2,
    const float* __restrict__ bf2, float* __restrict__ forces) {
    int lane = threadIdx.x & 63;
    int wv = blockIdx.x * 4 + (threadIdx.x >> 6);
    int base = wv * 8;
    int dbase = lane * 8;
    float wreg[16];
    #pragma unroll
    for (int s = 0; s < 2; ++s) {
        float4 a = *(const float4*)(Wf2 + s * 512 + dbase);
        float4 b = *(const float4*)(Wf2 + s * 512 + dbase + 4);
        wreg[s * 8 + 0] = a.x; wreg[s * 8 + 1] = a.y;
        wreg[s * 8 + 2] = a.z; wreg[s * 8 + 3] = a.w;
        wreg[s * 8 + 4] = b.x; wreg[s * 8 + 5] = b.y;
        wreg[s * 8 + 6] = b.z; wreg[s * 8 + 7] = b.w;
    }
    float bias2 = bf2[0];
    int cur = -1;
    float p0reg[16];
    float facc = 0.0f;
    #pragma unroll
    for (int j = 0; j < 8; ++j) {
        int e = sorted[base + j];
        int i0 = edge_index[e];
        int i1 = edge_index[EE + e];
        if (i0 != cur) {  // wave-uniform branch (e is uniform)
            if (cur >= 0 && lane < 3) atomicAdd(&forces[cur * 3 + lane], facc);
            facc = 0.0f;
            cur = i0;
            const unsigned short* p0 = P + (size_t)i0 * DD;
            #pragma unroll
            for (int s = 0; s < 2; ++s) {
                ushortx8 u0 = *(const ushortx8*)(p0 + s * 512 + dbase);
                #pragma unroll
                for (int jj = 0; jj < 8; ++jj)
                    p0reg[s * 8 + jj] = bf16_to_f32((unsigned short)u0[jj]);
            }
        }
        const unsigned short* p1 = P + (size_t)NNODES * DD + (size_t)i1 * DD;
        float acc = 0.0f;
        #pragma unroll
        for (int s = 0; s < 2; ++s) {
            ushortx8 u1 = *(const ushortx8*)(p1 + s * 512 + dbase);
            #pragma unroll
            for (int jj = 0; jj < 8; ++jj) {
                float hv = p0reg[s * 8 + jj] + bf16_to_f32((unsigned short)u1[jj]);
                acc = fmaf(gelu_fast(hv), wreg[s * 8 + jj], acc);
            }
        }
        #pragma unroll
        for (int off = 32; off > 0; off >>= 1) acc += __shfl_xor(acc, off, 64);
        float fm = acc + bias2;
        if (lane < 3) facc = fmaf(fm / edist[e], evec[e * 3 + lane], facc);
    }
    if (cur >= 0 && lane < 3) atomicAdd(&forces[cur * 3 + lane], facc);
}

extern "C" void kernel_launch(void* const* d_in, const int* in_sizes, int n_in,
                              void* d_out, int out_size, void* d_ws, size_t ws_size,
                              hipStream_t stream) {
    const float* x    = (const float*)d_in[0];
    const int* edge_index = (const int*)d_in[2];
    const float* evec = (const float*)d_in[3];
    const float* edist = (const float*)d_in[4];
    const float* ln_g = (const float*)d_in[6];
    const float* ln_b = (const float*)d_in[7];
    const float* We1  = (const float*)d_in[8];
    const float* be1  = (const float*)d_in[9];
    const float* We2  = (const float*)d_in[10];
    const float* be2  = (const float*)d_in[11];
    const float* Wf1  = (const float*)d_in[12];
    const float* bf1  = (const float*)d_in[13];
    const float* Wf2  = (const float*)d_in[14];
    const float* bf2  = (const float*)d_in[15];

    float* out = (float*)d_out;  // [0:32] energy, [32:32+6144] forces

    // ws layout:
    // [0, 8MB)        : P bf16 [2][2048][1024] -- first 1.125 MB doubles as
    //                   hnorm (128 KB) + He (1 MB) during the energy phase.
    // [8MB, 12MB)     : nodesB bf16 [2048][1024]
    // [12MB, 16MB)    : Wf1T  bf16 [2][1024][1024]
    // [16MB, +8KB)    : bins   int[2048]
    // [16MB+8KB,+8KB) : cursor int[2048]
    // [16MB+64KB, +256KB): sorted int[65536]
    char* wsb = (char*)d_ws;
    unsigned short* P      = (unsigned short*)(wsb);
    float* hnorm           = (float*)(wsb);
    float* He              = (float*)(wsb + (128 << 10));
    unsigned short* nodesB = (unsigned short*)(wsb + (8u << 20));
    unsigned short* Wf1T   = (unsigned short*)(wsb + (12u << 20));
    int* bins              = (int*)(wsb + (16u << 20));
    int* cursor            = (int*)(wsb + (16u << 20) + (8u << 10));
    int* sorted            = (int*)(wsb + (16u << 20) + (64u << 10));

    int total_out = BB + NNODES * 3;
    zero_out_kernel<<<(total_out + 255) / 256, 256, 0, stream>>>(out, total_out, bins);
    ln_kernel<<<BB, 256, 0, stream>>>(x, ln_g, ln_b, hnorm);
    energy1_kernel<<<dim3(4, 8, 2), 256, 0, stream>>>(hnorm, We1, He);
    energy2_kernel<<<BB, 256, 0, stream>>>(He, be1, We2, be2, out);
    hist_kernel<<<EE / 256, 256, 0, stream>>>(edge_index, bins);
    scan_kernel<<<1, 256, 0, stream>>>(bins, cursor);
    scatter_kernel<<<EE / 256, 256, 0, stream>>>(edge_index, cursor, sorted);
    prep_nodes_kernel<<<NNODES * DD / 1024, 256, 0, stream>>>(x, nodesB);
    prep_wf1t_kernel<<<dim3(32, 64), 256, 0, stream>>>(Wf1, Wf1T);
    pgemm_mfma_kernel<<<dim3(8, 32, 2), 256, 0, stream>>>(nodesB, Wf1T, bf1, P);
    edge_sorted_kernel<<<2048, 256, 0, stream>>>(P, sorted, edge_index, evec,
                                                 edist, Wf2, bf2, out + BB);
}

// Round 5
// 177.999 us; speedup vs baseline: 1.1577x; 1.1577x over previous
//
#include <hip/hip_runtime.h>
#include <math.h>

#define BB 32
#define TT 256
#define DD 1024
#define NNODES 2048
#define EE 65536
#define LN_EPS 1e-5f

typedef __attribute__((ext_vector_type(8))) short shortx8;
typedef __attribute__((ext_vector_type(4))) float floatx4;
typedef __attribute__((ext_vector_type(8))) unsigned short ushortx8;

__device__ __forceinline__ float gelu_fast(float x) {
    // tanh-approx gelu: x - x/(1+exp2(x*(2.302118 + 0.102945*x^2)))
    float x2 = x * x;
    float z = x * fmaf(0.10294456f, x2, 2.30211786f);
    float e = __builtin_amdgcn_exp2f(z);
    float r = __builtin_amdgcn_rcpf(1.0f + e);
    return fmaf(-x, r, x);
}

__device__ __forceinline__ unsigned short f32_to_bf16(float f) {
    unsigned u = __float_as_uint(f);
    unsigned r = (u + 0x7FFF + ((u >> 16) & 1)) >> 16;
    return (unsigned short)r;
}

__device__ __forceinline__ float bf16_to_f32(unsigned short h) {
    return __uint_as_float(((unsigned)h) << 16);
}

__device__ __forceinline__ void load_lds16(const void* g, void* l) {
    __builtin_amdgcn_global_load_lds(
        (const __attribute__((address_space(1))) void*)g,
        (__attribute__((address_space(3))) void*)l, 16, 0, 0);
}

// Fused: zero d_out (energy+forces) + LayerNorm of x[:,0,:]. grid=32, block=256.
__global__ void zero_ln_kernel(const float* __restrict__ x,
                               const float* __restrict__ g,
                               const float* __restrict__ bta,
                               float* __restrict__ hnorm,
                               float* __restrict__ out) {
    __shared__ float red[256];
    int b = blockIdx.x;
    int t = threadIdx.x;
    int zi = b * 256 + t;
    if (zi < BB + NNODES * 3) out[zi] = 0.0f;
    const float* row = x + (size_t)b * TT * DD;
    float v[4];
    float s = 0.0f;
    #pragma unroll
    for (int j = 0; j < 4; ++j) { v[j] = row[t + j * 256]; s += v[j]; }
    red[t] = s; __syncthreads();
    for (int off = 128; off > 0; off >>= 1) {
        if (t < off) red[t] += red[t + off];
        __syncthreads();
    }
    float mu = red[0] * (1.0f / DD);
    __syncthreads();
    float sq = 0.0f;
    #pragma unroll
    for (int j = 0; j < 4; ++j) { float d = v[j] - mu; sq += d * d; }
    red[t] = sq; __syncthreads();
    for (int off = 128; off > 0; off >>= 1) {
        if (t < off) red[t] += red[t + off];
        __syncthreads();
    }
    float rstd = rsqrtf(red[0] * (1.0f / DD) + LN_EPS);
    #pragma unroll
    for (int j = 0; j < 4; ++j) {
        int d = t + j * 256;
        hnorm[b * DD + d] = (v[j] - mu) * rstd * g[d] + bta[d];
    }
}

// Split-K/row partial GEMM: He[ks][r0+r][col] = sum_{64k chunk} h[r][k]*We1[k][col]
// grid (4 col-tiles of 256, 16 k-splits of 64, 2 row-groups of 16), block 256.
// 128 blocks (vs R3's 64): twice the CU coverage for this latency-bound kernel.
__global__ __launch_bounds__(256) void energy1_kernel(
    const float* __restrict__ hnorm, const float* __restrict__ We1,
    float* __restrict__ He) {
    __shared__ float hs[64 * 16];  // [k][r], broadcast reads
    int t = threadIdx.x;
    int col = blockIdx.x * 256 + t;
    int k0 = blockIdx.y * 64;
    int r0 = blockIdx.z * 16;
    for (int idx = t; idx < 64 * 16; idx += 256) {
        int r = idx & 15, k = idx >> 4;
        hs[idx] = hnorm[(size_t)(r0 + r) * DD + k0 + k];
    }
    __syncthreads();
    float acc[16];
    #pragma unroll
    for (int r = 0; r < 16; ++r) acc[r] = 0.0f;
    #pragma unroll 4
    for (int k = 0; k < 64; ++k) {
        float w = We1[(size_t)(k0 + k) * DD + col];
        const float* hrow = hs + k * 16;
        #pragma unroll
        for (int j = 0; j < 4; ++j) {
            float4 h4 = *(const float4*)(hrow + j * 4);
            acc[j * 4 + 0] = fmaf(h4.x, w, acc[j * 4 + 0]);
            acc[j * 4 + 1] = fmaf(h4.y, w, acc[j * 4 + 1]);
            acc[j * 4 + 2] = fmaf(h4.z, w, acc[j * 4 + 2]);
            acc[j * 4 + 3] = fmaf(h4.w, w, acc[j * 4 + 3]);
        }
    }
    float* o = He + (size_t)blockIdx.y * 32 * DD;
    #pragma unroll
    for (int r = 0; r < 16; ++r) o[(size_t)(r0 + r) * DD + col] = acc[r];
}

// Epilogue: sum 16 partials, gelu, dot We2. grid=32, block=256.
__global__ __launch_bounds__(256) void energy2_kernel(
    const float* __restrict__ He, const float* __restrict__ be1,
    const float* __restrict__ We2, const float* __restrict__ be2,
    float* __restrict__ out) {
    __shared__ float red[256];
    int b = blockIdx.x;
    int t = threadIdx.x;
    float p = 0.0f;
    #pragma unroll
    for (int j = 0; j < 4; ++j) {
        int c = t * 4 + j;
        float s = 0.0f;
        #pragma unroll
        for (int ks = 0; ks < 16; ++ks) s += He[(size_t)ks * 32 * DD + b * DD + c];
        s += be1[c];
        p += gelu_fast(s) * We2[c];
    }
    red[t] = p; __syncthreads();
    for (int off = 128; off > 0; off >>= 1) {
        if (t < off) red[t] += red[t + off];
        __syncthreads();
    }
    if (t == 0) out[b] = red[0] + be2[0];
}

// Fused prep: blocks [0,2048) convert x node slices -> bf16 nodesB;
// blocks [2048,4096) transpose Wf1 fp32 -> Wf1T bf16. block 256.
__global__ __launch_bounds__(256) void prep_kernel(
    const float* __restrict__ x, const float* __restrict__ Wf1,
    unsigned short* __restrict__ nodesB, unsigned short* __restrict__ Wf1T) {
    __shared__ float tile[32][33];
    if (blockIdx.x < 2048) {
        int idx4 = (blockIdx.x * 256 + threadIdx.x) * 4;
        int i = idx4 >> 10;
        int k = idx4 & 1023;
        const float* src = x + ((size_t)(i >> 6) * TT + 1 + (i & 63)) * DD + k;
        float4 v = *(const float4*)src;
        ushort4 o;
        o.x = f32_to_bf16(v.x); o.y = f32_to_bf16(v.y);
        o.z = f32_to_bf16(v.z); o.w = f32_to_bf16(v.w);
        *(ushort4*)&nodesB[idx4] = o;
    } else {
        int q = blockIdx.x - 2048;
        int tx = threadIdx.x & 31;
        int ty = threadIdx.x >> 5;
        int n0 = (q & 31) * 32;
        int kg0 = (q >> 5) * 32;
        #pragma unroll
        for (int j = 0; j < 4; ++j) {
            int r = ty * 4 + j;
            tile[r][tx] = Wf1[(size_t)(kg0 + r) * DD + n0 + tx];
        }
        __syncthreads();
        int half = kg0 >> 10;
        int kk0 = kg0 & 1023;
        unsigned short* o = Wf1T + (size_t)half * DD * DD;
        #pragma unroll
        for (int j = 0; j < 4; ++j) {
            int rn = ty * 4 + j;
            o[(size_t)(n0 + rn) * DD + kk0 + tx] = f32_to_bf16(tile[tx][rn]);
        }
    }
}

// MFMA GEMM (R3 config): P[half][i][n] = sum_k nodesB[i][k] * Wf1T[half][n][k]
// bf1 folded into half 0. Tile 128(n) x 128(i), BK=64.
// grid (8 n-tiles, 16 i-tiles, 2 halves) = 256 blocks, block 256.
__global__ __launch_bounds__(256) void pgemm_mfma_kernel(
    const unsigned short* __restrict__ nodesB,
    const unsigned short* __restrict__ Wf1T, const float* __restrict__ bf1,
    unsigned short* __restrict__ P) {
    __shared__ unsigned short As[128 * 64];  // [n-row][k], XOR-swizzled chunks
    __shared__ unsigned short Bs[128 * 64];  // [i-row][k]
    int t = threadIdx.x;
    int w = t >> 6;
    int lane = t & 63;
    int quad = lane >> 4;
    int l16 = lane & 15;
    int wn = (w & 1) * 64;
    int wi = (w >> 1) * 64;
    int half = blockIdx.z;
    int n0 = blockIdx.x * 128;
    int i0 = blockIdx.y * 128;

    const unsigned short* Ag = Wf1T + (size_t)half * DD * DD;
    const unsigned short* Bg = nodesB;

    int sr = lane >> 3;
    int sc = (lane & 7) ^ sr;
    size_t aoff[4], boff[4];
    #pragma unroll
    for (int j = 0; j < 4; ++j) {
        aoff[j] = (size_t)(n0 + w * 32 + j * 8 + sr) * DD + sc * 8;
        boff[j] = (size_t)(i0 + w * 32 + j * 8 + sr) * DD + sc * 8;
    }

    floatx4 acc[4][4];
    #pragma unroll
    for (int a = 0; a < 4; ++a)
        #pragma unroll
        for (int b = 0; b < 4; ++b) {
            acc[a][b][0] = 0.f; acc[a][b][1] = 0.f;
            acc[a][b][2] = 0.f; acc[a][b][3] = 0.f;
        }

    for (int k0 = 0; k0 < DD; k0 += 64) {
        #pragma unroll
        for (int j = 0; j < 4; ++j) {
            load_lds16(Ag + aoff[j] + k0, (void*)(As + (w * 32 + j * 8) * 64));
            load_lds16(Bg + boff[j] + k0, (void*)(Bs + (w * 32 + j * 8) * 64));
        }
        __syncthreads();
        #pragma unroll
        for (int s = 0; s < 2; ++s) {
            shortx8 af[4], bfr[4];
            #pragma unroll
            for (int f = 0; f < 4; ++f) {
                int rn = wn + f * 16 + l16;
                af[f] = *(const shortx8*)&As[rn * 64 + ((((s << 2) | quad) ^ (rn & 7)) << 3)];
                int ri = wi + f * 16 + l16;
                bfr[f] = *(const shortx8*)&Bs[ri * 64 + ((((s << 2) | quad) ^ (ri & 7)) << 3)];
            }
            #pragma unroll
            for (int fa = 0; fa < 4; ++fa)
                #pragma unroll
                for (int fb = 0; fb < 4; ++fb)
                    acc[fa][fb] = __builtin_amdgcn_mfma_f32_16x16x32_bf16(
                        af[fa], bfr[fb], acc[fa][fb], 0, 0, 0);
        }
        __syncthreads();
    }

    unsigned short* Pout = P + (size_t)half * NNODES * DD;
    #pragma unroll
    for (int fa = 0; fa < 4; ++fa) {
        int n = n0 + wn + fa * 16 + quad * 4;
        float4 badd = make_float4(0.f, 0.f, 0.f, 0.f);
        if (half == 0) badd = *(const float4*)(bf1 + n);
        #pragma unroll
        for (int fb = 0; fb < 4; ++fb) {
            int i = i0 + wi + fb * 16 + l16;
            floatx4 v = acc[fa][fb];
            ushort4 o;
            o.x = f32_to_bf16(v[0] + badd.x);
            o.y = f32_to_bf16(v[1] + badd.y);
            o.z = f32_to_bf16(v[2] + badd.z);
            o.w = f32_to_bf16(v[3] + badd.w);
            *(ushort4*)&Pout[(size_t)i * DD + n] = o;
        }
    }
}

// Edge kernel: wave handles 8 edges, 2 per iteration (interleaved loads for MLP,
// packed dual reduction: 7 shuffles per edge-pair vs 12). bf1 pre-folded in P.
// grid 2048 blocks x 256 (8192 waves).
__global__ __launch_bounds__(256) void edge_kernel(
    const unsigned short* __restrict__ P, const int* __restrict__ edge_index,
    const float* __restrict__ evec, const float* __restrict__ edist,
    const float* __restrict__ Wf2, const float* __restrict__ bf2,
    float* __restrict__ forces) {
    int lane = threadIdx.x & 63;
    int wv = blockIdx.x * 4 + (threadIdx.x >> 6);
    int dbase = lane * 8;
    float wreg[16];
    #pragma unroll
    for (int s = 0; s < 2; ++s) {
        float4 a = *(const float4*)(Wf2 + s * 512 + dbase);
        float4 b = *(const float4*)(Wf2 + s * 512 + dbase + 4);
        wreg[s * 8 + 0] = a.x; wreg[s * 8 + 1] = a.y;
        wreg[s * 8 + 2] = a.z; wreg[s * 8 + 3] = a.w;
        wreg[s * 8 + 4] = b.x; wreg[s * 8 + 5] = b.y;
        wreg[s * 8 + 6] = b.z; wreg[s * 8 + 7] = b.w;
    }
    float bias2 = bf2[0];
    const unsigned short* P1 = P + (size_t)NNODES * DD;
    #pragma unroll
    for (int it = 0; it < 4; ++it) {
        int ea = wv + (2 * it) * 8192;
        int eb = wv + (2 * it + 1) * 8192;
        int i0a = edge_index[ea], i1a = edge_index[EE + ea];
        int i0b = edge_index[eb], i1b = edge_index[EE + eb];
        const unsigned short* p0a = P + (size_t)i0a * DD + dbase;
        const unsigned short* p1a = P1 + (size_t)i1a * DD + dbase;
        const unsigned short* p0b = P + (size_t)i0b * DD + dbase;
        const unsigned short* p1b = P1 + (size_t)i1b * DD + dbase;
        ushortx8 u0a[2], u1a[2], u0b[2], u1b[2];
        #pragma unroll
        for (int s = 0; s < 2; ++s) {
            u0a[s] = *(const ushortx8*)(p0a + s * 512);
            u1a[s] = *(const ushortx8*)(p1a + s * 512);
            u0b[s] = *(const ushortx8*)(p0b + s * 512);
            u1b[s] = *(const ushortx8*)(p1b + s * 512);
        }
        float acca = 0.0f, accb = 0.0f;
        #pragma unroll
        for (int s = 0; s < 2; ++s) {
            #pragma unroll
            for (int j = 0; j < 8; ++j) {
                float ha = bf16_to_f32((unsigned short)u0a[s][j]) +
                           bf16_to_f32((unsigned short)u1a[s][j]);
                float hb = bf16_to_f32((unsigned short)u0b[s][j]) +
                           bf16_to_f32((unsigned short)u1b[s][j]);
                acca = fmaf(gelu_fast(ha), wreg[s * 8 + j], acca);
                accb = fmaf(gelu_fast(hb), wreg[s * 8 + j], accb);
            }
        }
        // fold halves, pack: lanes 0-31 carry edge a, lanes 32-63 edge b
        acca += __shfl_xor(acca, 32, 64);
        accb += __shfl_xor(accb, 32, 64);
        float red = (lane < 32) ? acca : accb;
        #pragma unroll
        for (int off = 16; off > 0; off >>= 1) red += __shfl_xor(red, off, 64);
        float fm = red + bias2;
        int l5 = lane & 31;
        if (l5 < 3) {
            int e = (lane < 32) ? ea : eb;
            int i0 = (lane < 32) ? i0a : i0b;
            float sc = fm / edist[e];
            atomicAdd(&forces[i0 * 3 + l5], sc * evec[e * 3 + l5]);
        }
    }
}

extern "C" void kernel_launch(void* const* d_in, const int* in_sizes, int n_in,
                              void* d_out, int out_size, void* d_ws, size_t ws_size,
                              hipStream_t stream) {
    const float* x    = (const float*)d_in[0];
    const int* edge_index = (const int*)d_in[2];
    const float* evec = (const float*)d_in[3];
    const float* edist = (const float*)d_in[4];
    const float* ln_g = (const float*)d_in[6];
    const float* ln_b = (const float*)d_in[7];
    const float* We1  = (const float*)d_in[8];
    const float* be1  = (const float*)d_in[9];
    const float* We2  = (const float*)d_in[10];
    const float* be2  = (const float*)d_in[11];
    const float* Wf1  = (const float*)d_in[12];
    const float* bf1  = (const float*)d_in[13];
    const float* Wf2  = (const float*)d_in[14];
    const float* bf2  = (const float*)d_in[15];

    float* out = (float*)d_out;  // [0:32] energy, [32:32+6144] forces

    // ws layout:
    // [0, 8MB)     : P bf16 [2][2048][1024] -- first 2.125 MB doubles as
    //                hnorm (128 KB) + He (2 MB) during the energy phase
    //                (P is written only after energy2 consumed them).
    // [8MB, 12MB)  : nodesB bf16 [2048][1024]
    // [12MB, 16MB) : Wf1T  bf16 [2][1024][1024]
    char* wsb = (char*)d_ws;
    unsigned short* P      = (unsigned short*)(wsb);
    float* hnorm           = (float*)(wsb);
    float* He              = (float*)(wsb + (128 << 10));
    unsigned short* nodesB = (unsigned short*)(wsb + (8u << 20));
    unsigned short* Wf1T   = (unsigned short*)(wsb + (12u << 20));

    zero_ln_kernel<<<BB, 256, 0, stream>>>(x, ln_g, ln_b, hnorm, out);
    energy1_kernel<<<dim3(4, 16, 2), 256, 0, stream>>>(hnorm, We1, He);
    energy2_kernel<<<BB, 256, 0, stream>>>(He, be1, We2, be2, out);
    prep_kernel<<<4096, 256, 0, stream>>>(x, Wf1, nodesB, Wf1T);
    pgemm_mfma_kernel<<<dim3(8, 16, 2), 256, 0, stream>>>(nodesB, Wf1T, bf1, P);
    edge_kernel<<<2048, 256, 0, stream>>>(P, edge_index, evec, edist, Wf2, bf2,
                                          out + BB);
}

// Round 6
// 158.020 us; speedup vs baseline: 1.3041x; 1.1264x over previous
//
#include <hip/hip_runtime.h>
#include <math.h>

#define BB 32
#define TT 256
#define DD 1024
#define NNODES 2048
#define EE 65536
#define LN_EPS 1e-5f

typedef __attribute__((ext_vector_type(8))) short shortx8;
typedef __attribute__((ext_vector_type(4))) float floatx4;
typedef __attribute__((ext_vector_type(8))) unsigned short ushortx8;

__device__ __forceinline__ float gelu_fast(float x) {
    // tanh-approx gelu: x - x/(1+exp2(x*(2.302118 + 0.102945*x^2)))
    float x2 = x * x;
    float z = x * fmaf(0.10294456f, x2, 2.30211786f);
    float e = __builtin_amdgcn_exp2f(z);
    float r = __builtin_amdgcn_rcpf(1.0f + e);
    return fmaf(-x, r, x);
}

__device__ __forceinline__ unsigned short f32_to_bf16(float f) {
    unsigned u = __float_as_uint(f);
    unsigned r = (u + 0x7FFF + ((u >> 16) & 1)) >> 16;
    return (unsigned short)r;
}

__device__ __forceinline__ float bf16_to_f32(unsigned short h) {
    return __uint_as_float(((unsigned)h) << 16);
}

__device__ __forceinline__ void load_lds16(const void* g, void* l) {
    __builtin_amdgcn_global_load_lds(
        (const __attribute__((address_space(1))) void*)g,
        (__attribute__((address_space(3))) void*)l, 16, 0, 0);
}

// ---------------- K1: zero d_out + LayerNorm (blocks 0..31) + prep (32..4127)
__global__ __launch_bounds__(256) void k1_zero_ln_prep_kernel(
    const float* __restrict__ x, const float* __restrict__ g,
    const float* __restrict__ bta, const float* __restrict__ Wf1,
    float* __restrict__ hnorm, float* __restrict__ out,
    unsigned short* __restrict__ nodesB, unsigned short* __restrict__ Wf1T) {
    __shared__ float smem[32 * 33];
    int t = threadIdx.x;
    int b = blockIdx.x;
    if (b < BB) {
        // zero d_out
        int zi = b * 256 + t;
        if (zi < BB + NNODES * 3) out[zi] = 0.0f;
        // LayerNorm row b
        float* red = smem;
        const float* row = x + (size_t)b * TT * DD;
        float v[4];
        float s = 0.0f;
        #pragma unroll
        for (int j = 0; j < 4; ++j) { v[j] = row[t + j * 256]; s += v[j]; }
        red[t] = s; __syncthreads();
        for (int off = 128; off > 0; off >>= 1) {
            if (t < off) red[t] += red[t + off];
            __syncthreads();
        }
        float mu = red[0] * (1.0f / DD);
        __syncthreads();
        float sq = 0.0f;
        #pragma unroll
        for (int j = 0; j < 4; ++j) { float d = v[j] - mu; sq += d * d; }
        red[t] = sq; __syncthreads();
        for (int off = 128; off > 0; off >>= 1) {
            if (t < off) red[t] += red[t + off];
            __syncthreads();
        }
        float rstd = rsqrtf(red[0] * (1.0f / DD) + LN_EPS);
        #pragma unroll
        for (int j = 0; j < 4; ++j) {
            int d = t + j * 256;
            hnorm[b * DD + d] = (v[j] - mu) * rstd * g[d] + bta[d];
        }
        return;
    }
    int pb = b - BB;
    if (pb < 2048) {
        // x node rows -> bf16 nodesB
        int idx4 = (pb * 256 + t) * 4;
        int i = idx4 >> 10;
        int k = idx4 & 1023;
        const float* src = x + ((size_t)(i >> 6) * TT + 1 + (i & 63)) * DD + k;
        float4 v = *(const float4*)src;
        ushort4 o;
        o.x = f32_to_bf16(v.x); o.y = f32_to_bf16(v.y);
        o.z = f32_to_bf16(v.z); o.w = f32_to_bf16(v.w);
        *(ushort4*)&nodesB[idx4] = o;
    } else {
        // Wf1 fp32 -> Wf1T bf16 (32x32 transpose tiles)
        int q = pb - 2048;
        float (*tile)[33] = (float(*)[33])smem;
        int tx = t & 31;
        int ty = t >> 5;
        int n0 = (q & 31) * 32;
        int kg0 = (q >> 5) * 32;
        #pragma unroll
        for (int j = 0; j < 4; ++j) {
            int r = ty * 4 + j;
            tile[r][tx] = Wf1[(size_t)(kg0 + r) * DD + n0 + tx];
        }
        __syncthreads();
        int half = kg0 >> 10;
        int kk0 = kg0 & 1023;
        unsigned short* o = Wf1T + (size_t)half * DD * DD;
        #pragma unroll
        for (int j = 0; j < 4; ++j) {
            int rn = ty * 4 + j;
            o[(size_t)(n0 + rn) * DD + kk0 + tx] = f32_to_bf16(tile[tx][rn]);
        }
    }
}

// ---------------- K2: MFMA pgemm (blocks 0..255, 512 thr = 8 waves) +
//                      energy1 split-K GEMM (blocks 256..319)
// pgemm: P[half][i][n] = sum_k nodesB[i][k]*Wf1T[half][n][k], bf1 folded in half0.
// Tile 128n x 128i, BK=64; wave tile 32n x 64i -> 2 waves/SIMD (R5 had 1).
__global__ __launch_bounds__(512) void k2_gemm_kernel(
    const unsigned short* __restrict__ nodesB,
    const unsigned short* __restrict__ Wf1T, const float* __restrict__ bf1,
    unsigned short* __restrict__ P, const float* __restrict__ hnorm,
    const float* __restrict__ We1, float* __restrict__ He) {
    __shared__ unsigned short smem[2 * 128 * 64];  // 32 KB
    int t = threadIdx.x;
    int b = blockIdx.x;
    if (b < 256) {
        unsigned short* As = smem;            // [n-row][k] XOR-swizzled chunks
        unsigned short* Bs = smem + 128 * 64; // [i-row][k]
        int w = t >> 6;         // 0..7
        int lane = t & 63;
        int quad = lane >> 4;
        int l16 = lane & 15;
        int wn = (w & 3) * 32;  // n-offset of wave tile
        int wi = (w >> 2) * 64; // i-offset of wave tile
        int n0 = (b & 7) * 128;
        int i0 = ((b >> 3) & 15) * 128;
        int half = b >> 7;

        const unsigned short* Ag = Wf1T + (size_t)half * DD * DD;
        const unsigned short* Bg = nodesB;

        int sr = lane >> 3;          // row within 8-row group
        int sc = (lane & 7) ^ sr;    // swizzled source chunk
        size_t aoff[2], boff[2];
        #pragma unroll
        for (int j = 0; j < 2; ++j) {
            int row = w * 16 + j * 8;
            aoff[j] = (size_t)(n0 + row + sr) * DD + sc * 8;
            boff[j] = (size_t)(i0 + row + sr) * DD + sc * 8;
        }

        floatx4 acc[2][4];
        #pragma unroll
        for (int a = 0; a < 2; ++a)
            #pragma unroll
            for (int c = 0; c < 4; ++c) {
                acc[a][c][0] = 0.f; acc[a][c][1] = 0.f;
                acc[a][c][2] = 0.f; acc[a][c][3] = 0.f;
            }

        for (int k0 = 0; k0 < DD; k0 += 64) {
            #pragma unroll
            for (int j = 0; j < 2; ++j) {
                int row = w * 16 + j * 8;
                load_lds16(Ag + aoff[j] + k0, (void*)(As + row * 64));
                load_lds16(Bg + boff[j] + k0, (void*)(Bs + row * 64));
            }
            __syncthreads();
            #pragma unroll
            for (int s = 0; s < 2; ++s) {
                shortx8 af[2], bfr[4];
                #pragma unroll
                for (int f = 0; f < 2; ++f) {
                    int rn = wn + f * 16 + l16;
                    af[f] = *(const shortx8*)&As[rn * 64 + ((((s << 2) | quad) ^ (rn & 7)) << 3)];
                }
                #pragma unroll
                for (int f = 0; f < 4; ++f) {
                    int ri = wi + f * 16 + l16;
                    bfr[f] = *(const shortx8*)&Bs[ri * 64 + ((((s << 2) | quad) ^ (ri & 7)) << 3)];
                }
                #pragma unroll
                for (int fa = 0; fa < 2; ++fa)
                    #pragma unroll
                    for (int fb = 0; fb < 4; ++fb)
                        acc[fa][fb] = __builtin_amdgcn_mfma_f32_16x16x32_bf16(
                            af[fa], bfr[fb], acc[fa][fb], 0, 0, 0);
            }
            __syncthreads();
        }

        unsigned short* Pout = P + (size_t)half * NNODES * DD;
        #pragma unroll
        for (int fa = 0; fa < 2; ++fa) {
            int n = n0 + wn + fa * 16 + quad * 4;
            float4 badd = make_float4(0.f, 0.f, 0.f, 0.f);
            if (half == 0) badd = *(const float4*)(bf1 + n);
            #pragma unroll
            for (int fb = 0; fb < 4; ++fb) {
                int i = i0 + wi + fb * 16 + l16;
                floatx4 v = acc[fa][fb];
                ushort4 o;
                o.x = f32_to_bf16(v[0] + badd.x);
                o.y = f32_to_bf16(v[1] + badd.y);
                o.z = f32_to_bf16(v[2] + badd.z);
                o.w = f32_to_bf16(v[3] + badd.w);
                *(ushort4*)&Pout[(size_t)i * DD + n] = o;
            }
        }
        return;
    }
    // energy1: He[ks][r0+r][col] = sum_{64k chunk} h[r][k]*We1[k][col]
    // q decomposed: 2 col-tiles of 512, 16 k-splits of 64, 2 row-groups of 16.
    {
        int q = b - 256;
        float* hs = (float*)smem;  // [k][r] 64x16
        int col = (q & 1) * 512 + t;
        int k0 = ((q >> 1) & 15) * 64;
        int r0 = (q >> 5) * 16;
        for (int idx = t; idx < 64 * 16; idx += 512) {
            int r = idx & 15, k = idx >> 4;
            hs[idx] = hnorm[(size_t)(r0 + r) * DD + k0 + k];
        }
        __syncthreads();
        float acc[16];
        #pragma unroll
        for (int r = 0; r < 16; ++r) acc[r] = 0.0f;
        #pragma unroll 4
        for (int k = 0; k < 64; ++k) {
            float wv = We1[(size_t)(k0 + k) * DD + col];
            const float* hrow = hs + k * 16;
            #pragma unroll
            for (int j = 0; j < 4; ++j) {
                float4 h4 = *(const float4*)(hrow + j * 4);
                acc[j * 4 + 0] = fmaf(h4.x, wv, acc[j * 4 + 0]);
                acc[j * 4 + 1] = fmaf(h4.y, wv, acc[j * 4 + 1]);
                acc[j * 4 + 2] = fmaf(h4.z, wv, acc[j * 4 + 2]);
                acc[j * 4 + 3] = fmaf(h4.w, wv, acc[j * 4 + 3]);
            }
        }
        float* o = He + (size_t)((q >> 1) & 15) * 32 * DD;
        #pragma unroll
        for (int r = 0; r < 16; ++r) o[(size_t)(r0 + r) * DD + col] = acc[r];
    }
}

// ---------------- K3: edge kernel (blocks 0..2047) + energy2 (2048..2079)
__global__ __launch_bounds__(256) void k3_edge_energy2_kernel(
    const unsigned short* __restrict__ P, const int* __restrict__ edge_index,
    const float* __restrict__ evec, const float* __restrict__ edist,
    const float* __restrict__ Wf2, const float* __restrict__ bf2,
    const float* __restrict__ He, const float* __restrict__ be1,
    const float* __restrict__ We2, const float* __restrict__ be2,
    float* __restrict__ out) {
    __shared__ float red[256];
    int t = threadIdx.x;
    int b = blockIdx.x;
    if (b < 2048) {
        float* forces = out + BB;
        int lane = t & 63;
        int wv = b * 4 + (t >> 6);
        int dbase = lane * 8;
        float wreg[16];
        #pragma unroll
        for (int s = 0; s < 2; ++s) {
            float4 a = *(const float4*)(Wf2 + s * 512 + dbase);
            float4 c = *(const float4*)(Wf2 + s * 512 + dbase + 4);
            wreg[s * 8 + 0] = a.x; wreg[s * 8 + 1] = a.y;
            wreg[s * 8 + 2] = a.z; wreg[s * 8 + 3] = a.w;
            wreg[s * 8 + 4] = c.x; wreg[s * 8 + 5] = c.y;
            wreg[s * 8 + 6] = c.z; wreg[s * 8 + 7] = c.w;
        }
        float bias2 = bf2[0];
        const unsigned short* P1 = P + (size_t)NNODES * DD;
        #pragma unroll
        for (int it = 0; it < 4; ++it) {
            int ea = wv + (2 * it) * 8192;
            int eb = wv + (2 * it + 1) * 8192;
            int i0a = edge_index[ea], i1a = edge_index[EE + ea];
            int i0b = edge_index[eb], i1b = edge_index[EE + eb];
            const unsigned short* p0a = P + (size_t)i0a * DD + dbase;
            const unsigned short* p1a = P1 + (size_t)i1a * DD + dbase;
            const unsigned short* p0b = P + (size_t)i0b * DD + dbase;
            const unsigned short* p1b = P1 + (size_t)i1b * DD + dbase;
            ushortx8 u0a[2], u1a[2], u0b[2], u1b[2];
            #pragma unroll
            for (int s = 0; s < 2; ++s) {
                u0a[s] = *(const ushortx8*)(p0a + s * 512);
                u1a[s] = *(const ushortx8*)(p1a + s * 512);
                u0b[s] = *(const ushortx8*)(p0b + s * 512);
                u1b[s] = *(const ushortx8*)(p1b + s * 512);
            }
            float acca = 0.0f, accb = 0.0f;
            #pragma unroll
            for (int s = 0; s < 2; ++s) {
                #pragma unroll
                for (int j = 0; j < 8; ++j) {
                    float ha = bf16_to_f32((unsigned short)u0a[s][j]) +
                               bf16_to_f32((unsigned short)u1a[s][j]);
                    float hb = bf16_to_f32((unsigned short)u0b[s][j]) +
                               bf16_to_f32((unsigned short)u1b[s][j]);
                    acca = fmaf(gelu_fast(ha), wreg[s * 8 + j], acca);
                    accb = fmaf(gelu_fast(hb), wreg[s * 8 + j], accb);
                }
            }
            // fold halves, pack: lanes 0-31 carry edge a, lanes 32-63 edge b
            acca += __shfl_xor(acca, 32, 64);
            accb += __shfl_xor(accb, 32, 64);
            float r = (lane < 32) ? acca : accb;
            #pragma unroll
            for (int off = 16; off > 0; off >>= 1) r += __shfl_xor(r, off, 64);
            float fm = r + bias2;
            int l5 = lane & 31;
            if (l5 < 3) {
                int e = (lane < 32) ? ea : eb;
                int i0 = (lane < 32) ? i0a : i0b;
                float sc = fm / edist[e];
                atomicAdd(&forces[i0 * 3 + l5], sc * evec[e * 3 + l5]);
            }
        }
        return;
    }
    // energy2: sum 16 partials, gelu, dot We2
    {
        int bb = b - 2048;
        float p = 0.0f;
        #pragma unroll
        for (int j = 0; j < 4; ++j) {
            int c = t * 4 + j;
            float s = 0.0f;
            #pragma unroll
            for (int ks = 0; ks < 16; ++ks)
                s += He[(size_t)ks * 32 * DD + bb * DD + c];
            s += be1[c];
            p += gelu_fast(s) * We2[c];
        }
        red[t] = p; __syncthreads();
        for (int off = 128; off > 0; off >>= 1) {
            if (t < off) red[t] += red[t + off];
            __syncthreads();
        }
        if (t == 0) out[bb] = red[0] + be2[0];
    }
}

extern "C" void kernel_launch(void* const* d_in, const int* in_sizes, int n_in,
                              void* d_out, int out_size, void* d_ws, size_t ws_size,
                              hipStream_t stream) {
    const float* x    = (const float*)d_in[0];
    const int* edge_index = (const int*)d_in[2];
    const float* evec = (const float*)d_in[3];
    const float* edist = (const float*)d_in[4];
    const float* ln_g = (const float*)d_in[6];
    const float* ln_b = (const float*)d_in[7];
    const float* We1  = (const float*)d_in[8];
    const float* be1  = (const float*)d_in[9];
    const float* We2  = (const float*)d_in[10];
    const float* be2  = (const float*)d_in[11];
    const float* Wf1  = (const float*)d_in[12];
    const float* bf1  = (const float*)d_in[13];
    const float* Wf2  = (const float*)d_in[14];
    const float* bf2  = (const float*)d_in[15];

    float* out = (float*)d_out;  // [0:32] energy, [32:32+6144] forces

    // ws layout:
    // [0, 8MB)     : P bf16 [2][2048][1024] -- first 2.125 MB doubles as
    //                hnorm (128 KB) + He (2 MB) during the energy phase
    //                (P is written only after energy2's inputs are consumed;
    //                 K2 writes P and He concurrently at disjoint offsets:
    //                 He lives at [128KB, 2.125MB) and P's first writes that
    //                 could alias come from half-0 i<544 tiles -- avoided by
    //                 placing He AFTER P region instead).
    // [8MB, 10MB+128KB) : hnorm (128 KB) + He (2 MB)
    // [11MB, 15MB) : nodesB bf16 [2048][1024]
    // [16MB, 20MB) : Wf1T  bf16 [2][1024][1024]
    char* wsb = (char*)d_ws;
    unsigned short* P      = (unsigned short*)(wsb);
    float* hnorm           = (float*)(wsb + (8u << 20));
    float* He              = (float*)(wsb + (8u << 20) + (128u << 10));
    unsigned short* nodesB = (unsigned short*)(wsb + (11u << 20));
    unsigned short* Wf1T   = (unsigned short*)(wsb + (16u << 20));

    k1_zero_ln_prep_kernel<<<4128, 256, 0, stream>>>(x, ln_g, ln_b, Wf1, hnorm,
                                                     out, nodesB, Wf1T);
    k2_gemm_kernel<<<320, 512, 0, stream>>>(nodesB, Wf1T, bf1, P, hnorm, We1, He);
    k3_edge_energy2_kernel<<<2080, 256, 0, stream>>>(P, edge_index, evec, edist,
                                                     Wf2, bf2, He, be1, We2, be2,
                                                     out);
}

// Round 7
// 152.410 us; speedup vs baseline: 1.3521x; 1.0368x over previous
//
#include <hip/hip_runtime.h>
#include <math.h>

#define BB 32
#define TT 256
#define DD 1024
#define NNODES 2048
#define EE 65536
#define LN_EPS 1e-5f

typedef __attribute__((ext_vector_type(8))) short shortx8;
typedef __attribute__((ext_vector_type(4))) float floatx4;
typedef __attribute__((ext_vector_type(8))) unsigned short ushortx8;

__device__ __forceinline__ float gelu_fast(float x) {
    // tanh-approx gelu: x - x/(1+exp2(x*(2.302118 + 0.102945*x^2)))
    float x2 = x * x;
    float z = x * fmaf(0.10294456f, x2, 2.30211786f);
    float e = __builtin_amdgcn_exp2f(z);
    float r = __builtin_amdgcn_rcpf(1.0f + e);
    return fmaf(-x, r, x);
}

__device__ __forceinline__ float gelu_sig(float x) {
    // x * sigmoid(1.702 x) = x / (1 + exp2(-2.4554669 x)); 2 fewer VALU ops
    float e = __builtin_amdgcn_exp2f(-2.4554669f * x);
    float r = __builtin_amdgcn_rcpf(1.0f + e);
    return x * r;
}

__device__ __forceinline__ unsigned short f32_to_bf16(float f) {
    unsigned u = __float_as_uint(f);
    unsigned r = (u + 0x7FFF + ((u >> 16) & 1)) >> 16;
    return (unsigned short)r;
}

__device__ __forceinline__ float bf16_to_f32(unsigned short h) {
    return __uint_as_float(((unsigned)h) << 16);
}

__device__ __forceinline__ void load_lds16(const void* g, void* l) {
    __builtin_amdgcn_global_load_lds(
        (const __attribute__((address_space(1))) void*)g,
        (__attribute__((address_space(3))) void*)l, 16, 0, 0);
}

// ---------------- K1: zero d_out + LayerNorm (blocks 0..31) + prep (32..4127)
__global__ __launch_bounds__(256) void k1_zero_ln_prep_kernel(
    const float* __restrict__ x, const float* __restrict__ g,
    const float* __restrict__ bta, const float* __restrict__ Wf1,
    float* __restrict__ hnorm, float* __restrict__ out,
    unsigned short* __restrict__ nodesB, unsigned short* __restrict__ Wf1T) {
    __shared__ float smem[32 * 33];
    int t = threadIdx.x;
    int b = blockIdx.x;
    if (b < BB) {
        int zi = b * 256 + t;
        if (zi < BB + NNODES * 3) out[zi] = 0.0f;
        float* red = smem;
        const float* row = x + (size_t)b * TT * DD;
        float v[4];
        float s = 0.0f;
        #pragma unroll
        for (int j = 0; j < 4; ++j) { v[j] = row[t + j * 256]; s += v[j]; }
        red[t] = s; __syncthreads();
        for (int off = 128; off > 0; off >>= 1) {
            if (t < off) red[t] += red[t + off];
            __syncthreads();
        }
        float mu = red[0] * (1.0f / DD);
        __syncthreads();
        float sq = 0.0f;
        #pragma unroll
        for (int j = 0; j < 4; ++j) { float d = v[j] - mu; sq += d * d; }
        red[t] = sq; __syncthreads();
        for (int off = 128; off > 0; off >>= 1) {
            if (t < off) red[t] += red[t + off];
            __syncthreads();
        }
        float rstd = rsqrtf(red[0] * (1.0f / DD) + LN_EPS);
        #pragma unroll
        for (int j = 0; j < 4; ++j) {
            int d = t + j * 256;
            hnorm[b * DD + d] = (v[j] - mu) * rstd * g[d] + bta[d];
        }
        return;
    }
    int pb = b - BB;
    if (pb < 2048) {
        int idx4 = (pb * 256 + t) * 4;
        int i = idx4 >> 10;
        int k = idx4 & 1023;
        const float* src = x + ((size_t)(i >> 6) * TT + 1 + (i & 63)) * DD + k;
        float4 v = *(const float4*)src;
        ushort4 o;
        o.x = f32_to_bf16(v.x); o.y = f32_to_bf16(v.y);
        o.z = f32_to_bf16(v.z); o.w = f32_to_bf16(v.w);
        *(ushort4*)&nodesB[idx4] = o;
    } else {
        int q = pb - 2048;
        float (*tile)[33] = (float(*)[33])smem;
        int tx = t & 31;
        int ty = t >> 5;
        int n0 = (q & 31) * 32;
        int kg0 = (q >> 5) * 32;
        #pragma unroll
        for (int j = 0; j < 4; ++j) {
            int r = ty * 4 + j;
            tile[r][tx] = Wf1[(size_t)(kg0 + r) * DD + n0 + tx];
        }
        __syncthreads();
        int half = kg0 >> 10;
        int kk0 = kg0 & 1023;
        unsigned short* o = Wf1T + (size_t)half * DD * DD;
        #pragma unroll
        for (int j = 0; j < 4; ++j) {
            int rn = ty * 4 + j;
            o[(size_t)(n0 + rn) * DD + kk0 + tx] = f32_to_bf16(tile[tx][rn]);
        }
    }
}

// ---------------- K2: MFMA pgemm (blocks 0..255, 512 thr = 8 waves) +
//                      energy1 split-K GEMM (blocks 256..319)
__global__ __launch_bounds__(512) void k2_gemm_kernel(
    const unsigned short* __restrict__ nodesB,
    const unsigned short* __restrict__ Wf1T, const float* __restrict__ bf1,
    unsigned short* __restrict__ P, const float* __restrict__ hnorm,
    const float* __restrict__ We1, float* __restrict__ He) {
    __shared__ unsigned short smem[2 * 128 * 64];  // 32 KB
    int t = threadIdx.x;
    int b = blockIdx.x;
    if (b < 256) {
        unsigned short* As = smem;            // [n-row][k] XOR-swizzled chunks
        unsigned short* Bs = smem + 128 * 64; // [i-row][k]
        int w = t >> 6;
        int lane = t & 63;
        int quad = lane >> 4;
        int l16 = lane & 15;
        int wn = (w & 3) * 32;
        int wi = (w >> 2) * 64;
        int n0 = (b & 7) * 128;
        int i0 = ((b >> 3) & 15) * 128;
        int half = b >> 7;

        const unsigned short* Ag = Wf1T + (size_t)half * DD * DD;
        const unsigned short* Bg = nodesB;

        int sr = lane >> 3;
        int sc = (lane & 7) ^ sr;
        size_t aoff[2], boff[2];
        #pragma unroll
        for (int j = 0; j < 2; ++j) {
            int row = w * 16 + j * 8;
            aoff[j] = (size_t)(n0 + row + sr) * DD + sc * 8;
            boff[j] = (size_t)(i0 + row + sr) * DD + sc * 8;
        }

        floatx4 acc[2][4];
        #pragma unroll
        for (int a = 0; a < 2; ++a)
            #pragma unroll
            for (int c = 0; c < 4; ++c) {
                acc[a][c][0] = 0.f; acc[a][c][1] = 0.f;
                acc[a][c][2] = 0.f; acc[a][c][3] = 0.f;
            }

        for (int k0 = 0; k0 < DD; k0 += 64) {
            #pragma unroll
            for (int j = 0; j < 2; ++j) {
                int row = w * 16 + j * 8;
                load_lds16(Ag + aoff[j] + k0, (void*)(As + row * 64));
                load_lds16(Bg + boff[j] + k0, (void*)(Bs + row * 64));
            }
            __syncthreads();
            #pragma unroll
            for (int s = 0; s < 2; ++s) {
                shortx8 af[2], bfr[4];
                #pragma unroll
                for (int f = 0; f < 2; ++f) {
                    int rn = wn + f * 16 + l16;
                    af[f] = *(const shortx8*)&As[rn * 64 + ((((s << 2) | quad) ^ (rn & 7)) << 3)];
                }
                #pragma unroll
                for (int f = 0; f < 4; ++f) {
                    int ri = wi + f * 16 + l16;
                    bfr[f] = *(const shortx8*)&Bs[ri * 64 + ((((s << 2) | quad) ^ (ri & 7)) << 3)];
                }
                #pragma unroll
                for (int fa = 0; fa < 2; ++fa)
                    #pragma unroll
                    for (int fb = 0; fb < 4; ++fb)
                        acc[fa][fb] = __builtin_amdgcn_mfma_f32_16x16x32_bf16(
                            af[fa], bfr[fb], acc[fa][fb], 0, 0, 0);
            }
            __syncthreads();
        }

        unsigned short* Pout = P + (size_t)half * NNODES * DD;
        #pragma unroll
        for (int fa = 0; fa < 2; ++fa) {
            int n = n0 + wn + fa * 16 + quad * 4;
            float4 badd = make_float4(0.f, 0.f, 0.f, 0.f);
            if (half == 0) badd = *(const float4*)(bf1 + n);
            #pragma unroll
            for (int fb = 0; fb < 4; ++fb) {
                int i = i0 + wi + fb * 16 + l16;
                floatx4 v = acc[fa][fb];
                ushort4 o;
                o.x = f32_to_bf16(v[0] + badd.x);
                o.y = f32_to_bf16(v[1] + badd.y);
                o.z = f32_to_bf16(v[2] + badd.z);
                o.w = f32_to_bf16(v[3] + badd.w);
                *(ushort4*)&Pout[(size_t)i * DD + n] = o;
            }
        }
        return;
    }
    // energy1: He[ks][r0+r][col] = sum_{64k chunk} h[r][k]*We1[k][col]
    {
        int q = b - 256;
        float* hs = (float*)smem;  // [k][r] 64x16
        int col = (q & 1) * 512 + t;
        int k0 = ((q >> 1) & 15) * 64;
        int r0 = (q >> 5) * 16;
        for (int idx = t; idx < 64 * 16; idx += 512) {
            int r = idx & 15, k = idx >> 4;
            hs[idx] = hnorm[(size_t)(r0 + r) * DD + k0 + k];
        }
        __syncthreads();
        float acc[16];
        #pragma unroll
        for (int r = 0; r < 16; ++r) acc[r] = 0.0f;
        #pragma unroll 4
        for (int k = 0; k < 64; ++k) {
            float wv = We1[(size_t)(k0 + k) * DD + col];
            const float* hrow = hs + k * 16;
            #pragma unroll
            for (int j = 0; j < 4; ++j) {
                float4 h4 = *(const float4*)(hrow + j * 4);
                acc[j * 4 + 0] = fmaf(h4.x, wv, acc[j * 4 + 0]);
                acc[j * 4 + 1] = fmaf(h4.y, wv, acc[j * 4 + 1]);
                acc[j * 4 + 2] = fmaf(h4.z, wv, acc[j * 4 + 2]);
                acc[j * 4 + 3] = fmaf(h4.w, wv, acc[j * 4 + 3]);
            }
        }
        float* o = He + (size_t)((q >> 1) & 15) * 32 * DD;
        #pragma unroll
        for (int r = 0; r < 16; ++r) o[(size_t)(r0 + r) * DD + col] = acc[r];
    }
}

// ---------------- K3: edge kernel (blocks 0..2047) + energy2 (2048..2079)
// Edge path: 8 edges per wave, processed as 4 pairs with one-pair-ahead
// register double-buffering (prefetch next pair's 8 P-row fragments while
// computing the current pair); indices hoisted to SGPRs via readfirstlane.
__global__ __launch_bounds__(256) void k3_edge_energy2_kernel(
    const unsigned short* __restrict__ P, const int* __restrict__ edge_index,
    const float* __restrict__ evec, const float* __restrict__ edist,
    const float* __restrict__ Wf2, const float* __restrict__ bf2,
    const float* __restrict__ He, const float* __restrict__ be1,
    const float* __restrict__ We2, const float* __restrict__ be2,
    float* __restrict__ out) {
    __shared__ float red[256];
    int t = threadIdx.x;
    int b = blockIdx.x;
    if (b < 2048) {
        float* forces = out + BB;
        int lane = t & 63;
        int wv = b * 4 + (t >> 6);
        int dbase = lane * 8;
        float wreg[16];
        #pragma unroll
        for (int s = 0; s < 2; ++s) {
            float4 a = *(const float4*)(Wf2 + s * 512 + dbase);
            float4 c = *(const float4*)(Wf2 + s * 512 + dbase + 4);
            wreg[s * 8 + 0] = a.x; wreg[s * 8 + 1] = a.y;
            wreg[s * 8 + 2] = a.z; wreg[s * 8 + 3] = a.w;
            wreg[s * 8 + 4] = c.x; wreg[s * 8 + 5] = c.y;
            wreg[s * 8 + 6] = c.z; wreg[s * 8 + 7] = c.w;
        }
        float bias2 = bf2[0];
        const unsigned short* P1 = P + (size_t)NNODES * DD;

        // hoist all 8 edges' endpoints into SGPRs (wave-uniform)
        int i0v[8], i1v[8];
        #pragma unroll
        for (int j = 0; j < 8; ++j) {
            int e = wv + j * 8192;
            i0v[j] = __builtin_amdgcn_readfirstlane(edge_index[e]);
            i1v[j] = __builtin_amdgcn_readfirstlane(edge_index[EE + e]);
        }

        // double-buffered row fragments: [buf][0..1]=p0a seg0/1, [2..3]=p1a,
        // [4..5]=p0b, [6..7]=p1b
        ushortx8 buf[2][8];
        #pragma unroll
        for (int s = 0; s < 2; ++s) {
            buf[0][0 + s] = *(const ushortx8*)(P  + (size_t)i0v[0] * DD + dbase + s * 512);
            buf[0][2 + s] = *(const ushortx8*)(P1 + (size_t)i1v[0] * DD + dbase + s * 512);
            buf[0][4 + s] = *(const ushortx8*)(P  + (size_t)i0v[1] * DD + dbase + s * 512);
            buf[0][6 + s] = *(const ushortx8*)(P1 + (size_t)i1v[1] * DD + dbase + s * 512);
        }
        #pragma unroll
        for (int it = 0; it < 4; ++it) {
            if (it < 3) {
                int ja = 2 * it + 2, jb = 2 * it + 3;
                ushortx8* nb = buf[(it + 1) & 1];
                #pragma unroll
                for (int s = 0; s < 2; ++s) {
                    nb[0 + s] = *(const ushortx8*)(P  + (size_t)i0v[ja] * DD + dbase + s * 512);
                    nb[2 + s] = *(const ushortx8*)(P1 + (size_t)i1v[ja] * DD + dbase + s * 512);
                    nb[4 + s] = *(const ushortx8*)(P  + (size_t)i0v[jb] * DD + dbase + s * 512);
                    nb[6 + s] = *(const ushortx8*)(P1 + (size_t)i1v[jb] * DD + dbase + s * 512);
                }
            }
            const ushortx8* cb = buf[it & 1];
            float acca = 0.0f, accb = 0.0f;
            #pragma unroll
            for (int s = 0; s < 2; ++s) {
                #pragma unroll
                for (int j = 0; j < 8; ++j) {
                    float ha = bf16_to_f32((unsigned short)cb[0 + s][j]) +
                               bf16_to_f32((unsigned short)cb[2 + s][j]);
                    float hb = bf16_to_f32((unsigned short)cb[4 + s][j]) +
                               bf16_to_f32((unsigned short)cb[6 + s][j]);
                    acca = fmaf(gelu_sig(ha), wreg[s * 8 + j], acca);
                    accb = fmaf(gelu_sig(hb), wreg[s * 8 + j], accb);
                }
            }
            // fold halves, pack: lanes 0-31 carry edge a, lanes 32-63 edge b
            acca += __shfl_xor(acca, 32, 64);
            accb += __shfl_xor(accb, 32, 64);
            float r = (lane < 32) ? acca : accb;
            #pragma unroll
            for (int off = 16; off > 0; off >>= 1) r += __shfl_xor(r, off, 64);
            float fm = r + bias2;
            int l5 = lane & 31;
            if (l5 < 3) {
                int e = (lane < 32) ? (wv + (2 * it) * 8192) : (wv + (2 * it + 1) * 8192);
                int i0 = (lane < 32) ? i0v[2 * it] : i0v[2 * it + 1];
                float sc = fm / edist[e];
                atomicAdd(&forces[i0 * 3 + l5], sc * evec[e * 3 + l5]);
            }
        }
        return;
    }
    // energy2: sum 16 partials, gelu, dot We2
    {
        int bb = b - 2048;
        float p = 0.0f;
        #pragma unroll
        for (int j = 0; j < 4; ++j) {
            int c = t * 4 + j;
            float s = 0.0f;
            #pragma unroll
            for (int ks = 0; ks < 16; ++ks)
                s += He[(size_t)ks * 32 * DD + bb * DD + c];
            s += be1[c];
            p += gelu_fast(s) * We2[c];
        }
        red[t] = p; __syncthreads();
        for (int off = 128; off > 0; off >>= 1) {
            if (t < off) red[t] += red[t + off];
            __syncthreads();
        }
        if (t == 0) out[bb] = red[0] + be2[0];
    }
}

extern "C" void kernel_launch(void* const* d_in, const int* in_sizes, int n_in,
                              void* d_out, int out_size, void* d_ws, size_t ws_size,
                              hipStream_t stream) {
    const float* x    = (const float*)d_in[0];
    const int* edge_index = (const int*)d_in[2];
    const float* evec = (const float*)d_in[3];
    const float* edist = (const float*)d_in[4];
    const float* ln_g = (const float*)d_in[6];
    const float* ln_b = (const float*)d_in[7];
    const float* We1  = (const float*)d_in[8];
    const float* be1  = (const float*)d_in[9];
    const float* We2  = (const float*)d_in[10];
    const float* be2  = (const float*)d_in[11];
    const float* Wf1  = (const float*)d_in[12];
    const float* bf1  = (const float*)d_in[13];
    const float* Wf2  = (const float*)d_in[14];
    const float* bf2  = (const float*)d_in[15];

    float* out = (float*)d_out;  // [0:32] energy, [32:32+6144] forces

    // ws layout:
    // [0, 8MB)          : P bf16 [2][2048][1024]
    // [8MB, 10MB+128KB) : hnorm (128 KB) + He (2 MB)
    // [11MB, 15MB)      : nodesB bf16 [2048][1024]
    // [16MB, 20MB)      : Wf1T  bf16 [2][1024][1024]
    char* wsb = (char*)d_ws;
    unsigned short* P      = (unsigned short*)(wsb);
    float* hnorm           = (float*)(wsb + (8u << 20));
    float* He              = (float*)(wsb + (8u << 20) + (128u << 10));
    unsigned short* nodesB = (unsigned short*)(wsb + (11u << 20));
    unsigned short* Wf1T   = (unsigned short*)(wsb + (16u << 20));

    k1_zero_ln_prep_kernel<<<4128, 256, 0, stream>>>(x, ln_g, ln_b, Wf1, hnorm,
                                                     out, nodesB, Wf1T);
    k2_gemm_kernel<<<320, 512, 0, stream>>>(nodesB, Wf1T, bf1, P, hnorm, We1, He);
    k3_edge_energy2_kernel<<<2080, 256, 0, stream>>>(P, edge_index, evec, edist,
                                                     Wf2, bf2, He, be1, We2, be2,
                                                     out);
}

// Round 8
// 152.277 us; speedup vs baseline: 1.3533x; 1.0009x over previous
//
#include <hip/hip_runtime.h>
#include <math.h>

#define BB 32
#define TT 256
#define DD 1024
#define NNODES 2048
#define EE 65536
#define LN_EPS 1e-5f

typedef __attribute__((ext_vector_type(8))) short shortx8;
typedef __attribute__((ext_vector_type(4))) float floatx4;
typedef __attribute__((ext_vector_type(8))) unsigned short ushortx8;

__device__ __forceinline__ float gelu_fast(float x) {
    // tanh-approx gelu: x - x/(1+exp2(x*(2.302118 + 0.102945*x^2)))
    float x2 = x * x;
    float z = x * fmaf(0.10294456f, x2, 2.30211786f);
    float e = __builtin_amdgcn_exp2f(z);
    float r = __builtin_amdgcn_rcpf(1.0f + e);
    return fmaf(-x, r, x);
}

__device__ __forceinline__ float gelu_sig(float x) {
    // x * sigmoid(1.702 x) = x / (1 + exp2(-2.4554669 x))
    float e = __builtin_amdgcn_exp2f(-2.4554669f * x);
    float r = __builtin_amdgcn_rcpf(1.0f + e);
    return x * r;
}

__device__ __forceinline__ unsigned short f32_to_bf16(float f) {
    unsigned u = __float_as_uint(f);
    unsigned r = (u + 0x7FFF + ((u >> 16) & 1)) >> 16;
    return (unsigned short)r;
}

__device__ __forceinline__ float bf16_to_f32(unsigned short h) {
    return __uint_as_float(((unsigned)h) << 16);
}

__device__ __forceinline__ void load_lds16(const void* g, void* l) {
    __builtin_amdgcn_global_load_lds(
        (const __attribute__((address_space(1))) void*)g,
        (__attribute__((address_space(3))) void*)l, 16, 0, 0);
}

// ---------------- K1: zero d_out + LayerNorm (blocks 0..31) + prep (32..4127)
__global__ __launch_bounds__(256) void k1_zero_ln_prep_kernel(
    const float* __restrict__ x, const float* __restrict__ g,
    const float* __restrict__ bta, const float* __restrict__ Wf1,
    float* __restrict__ hnorm, float* __restrict__ out,
    unsigned short* __restrict__ nodesB, unsigned short* __restrict__ Wf1T) {
    __shared__ float smem[32 * 33];
    int t = threadIdx.x;
    int b = blockIdx.x;
    if (b < BB) {
        int zi = b * 256 + t;
        if (zi < BB + NNODES * 3) out[zi] = 0.0f;
        float* red = smem;
        const float* row = x + (size_t)b * TT * DD;
        float v[4];
        float s = 0.0f;
        #pragma unroll
        for (int j = 0; j < 4; ++j) { v[j] = row[t + j * 256]; s += v[j]; }
        red[t] = s; __syncthreads();
        for (int off = 128; off > 0; off >>= 1) {
            if (t < off) red[t] += red[t + off];
            __syncthreads();
        }
        float mu = red[0] * (1.0f / DD);
        __syncthreads();
        float sq = 0.0f;
        #pragma unroll
        for (int j = 0; j < 4; ++j) { float d = v[j] - mu; sq += d * d; }
        red[t] = sq; __syncthreads();
        for (int off = 128; off > 0; off >>= 1) {
            if (t < off) red[t] += red[t + off];
            __syncthreads();
        }
        float rstd = rsqrtf(red[0] * (1.0f / DD) + LN_EPS);
        #pragma unroll
        for (int j = 0; j < 4; ++j) {
            int d = t + j * 256;
            hnorm[b * DD + d] = (v[j] - mu) * rstd * g[d] + bta[d];
        }
        return;
    }
    int pb = b - BB;
    if (pb < 2048) {
        int idx4 = (pb * 256 + t) * 4;
        int i = idx4 >> 10;
        int k = idx4 & 1023;
        const float* src = x + ((size_t)(i >> 6) * TT + 1 + (i & 63)) * DD + k;
        float4 v = *(const float4*)src;
        ushort4 o;
        o.x = f32_to_bf16(v.x); o.y = f32_to_bf16(v.y);
        o.z = f32_to_bf16(v.z); o.w = f32_to_bf16(v.w);
        *(ushort4*)&nodesB[idx4] = o;
    } else {
        int q = pb - 2048;
        float (*tile)[33] = (float(*)[33])smem;
        int tx = t & 31;
        int ty = t >> 5;
        int n0 = (q & 31) * 32;
        int kg0 = (q >> 5) * 32;
        #pragma unroll
        for (int j = 0; j < 4; ++j) {
            int r = ty * 4 + j;
            tile[r][tx] = Wf1[(size_t)(kg0 + r) * DD + n0 + tx];
        }
        __syncthreads();
        int half = kg0 >> 10;
        int kk0 = kg0 & 1023;
        unsigned short* o = Wf1T + (size_t)half * DD * DD;
        #pragma unroll
        for (int j = 0; j < 4; ++j) {
            int rn = ty * 4 + j;
            o[(size_t)(n0 + rn) * DD + kk0 + tx] = f32_to_bf16(tile[tx][rn]);
        }
    }
}

// ---------------- K2: MFMA pgemm (blocks 0..255, 512 thr = 8 waves) +
//                      energy1 split-K GEMM (blocks 256..319)
__global__ __launch_bounds__(512) void k2_gemm_kernel(
    const unsigned short* __restrict__ nodesB,
    const unsigned short* __restrict__ Wf1T, const float* __restrict__ bf1,
    unsigned short* __restrict__ P, const float* __restrict__ hnorm,
    const float* __restrict__ We1, float* __restrict__ He) {
    __shared__ unsigned short smem[2 * 128 * 64];  // 32 KB
    int t = threadIdx.x;
    int b = blockIdx.x;
    if (b < 256) {
        unsigned short* As = smem;            // [n-row][k] XOR-swizzled chunks
        unsigned short* Bs = smem + 128 * 64; // [i-row][k]
        int w = t >> 6;
        int lane = t & 63;
        int quad = lane >> 4;
        int l16 = lane & 15;
        int wn = (w & 3) * 32;
        int wi = (w >> 2) * 64;
        int n0 = (b & 7) * 128;
        int i0 = ((b >> 3) & 15) * 128;
        int half = b >> 7;

        const unsigned short* Ag = Wf1T + (size_t)half * DD * DD;
        const unsigned short* Bg = nodesB;

        int sr = lane >> 3;
        int sc = (lane & 7) ^ sr;
        size_t aoff[2], boff[2];
        #pragma unroll
        for (int j = 0; j < 2; ++j) {
            int row = w * 16 + j * 8;
            aoff[j] = (size_t)(n0 + row + sr) * DD + sc * 8;
            boff[j] = (size_t)(i0 + row + sr) * DD + sc * 8;
        }

        floatx4 acc[2][4];
        #pragma unroll
        for (int a = 0; a < 2; ++a)
            #pragma unroll
            for (int c = 0; c < 4; ++c) {
                acc[a][c][0] = 0.f; acc[a][c][1] = 0.f;
                acc[a][c][2] = 0.f; acc[a][c][3] = 0.f;
            }

        for (int k0 = 0; k0 < DD; k0 += 64) {
            #pragma unroll
            for (int j = 0; j < 2; ++j) {
                int row = w * 16 + j * 8;
                load_lds16(Ag + aoff[j] + k0, (void*)(As + row * 64));
                load_lds16(Bg + boff[j] + k0, (void*)(Bs + row * 64));
            }
            __syncthreads();
            #pragma unroll
            for (int s = 0; s < 2; ++s) {
                shortx8 af[2], bfr[4];
                #pragma unroll
                for (int f = 0; f < 2; ++f) {
                    int rn = wn + f * 16 + l16;
                    af[f] = *(const shortx8*)&As[rn * 64 + ((((s << 2) | quad) ^ (rn & 7)) << 3)];
                }
                #pragma unroll
                for (int f = 0; f < 4; ++f) {
                    int ri = wi + f * 16 + l16;
                    bfr[f] = *(const shortx8*)&Bs[ri * 64 + ((((s << 2) | quad) ^ (ri & 7)) << 3)];
                }
                #pragma unroll
                for (int fa = 0; fa < 2; ++fa)
                    #pragma unroll
                    for (int fb = 0; fb < 4; ++fb)
                        acc[fa][fb] = __builtin_amdgcn_mfma_f32_16x16x32_bf16(
                            af[fa], bfr[fb], acc[fa][fb], 0, 0, 0);
            }
            __syncthreads();
        }

        unsigned short* Pout = P + (size_t)half * NNODES * DD;
        #pragma unroll
        for (int fa = 0; fa < 2; ++fa) {
            int n = n0 + wn + fa * 16 + quad * 4;
            float4 badd = make_float4(0.f, 0.f, 0.f, 0.f);
            if (half == 0) badd = *(const float4*)(bf1 + n);
            #pragma unroll
            for (int fb = 0; fb < 4; ++fb) {
                int i = i0 + wi + fb * 16 + l16;
                floatx4 v = acc[fa][fb];
                ushort4 o;
                o.x = f32_to_bf16(v[0] + badd.x);
                o.y = f32_to_bf16(v[1] + badd.y);
                o.z = f32_to_bf16(v[2] + badd.z);
                o.w = f32_to_bf16(v[3] + badd.w);
                *(ushort4*)&Pout[(size_t)i * DD + n] = o;
            }
        }
        return;
    }
    // energy1: He[ks][r0+r][col] = sum_{64k chunk} h[r][k]*We1[k][col]
    {
        int q = b - 256;
        float* hs = (float*)smem;  // [k][r] 64x16
        int col = (q & 1) * 512 + t;
        int k0 = ((q >> 1) & 15) * 64;
        int r0 = (q >> 5) * 16;
        for (int idx = t; idx < 64 * 16; idx += 512) {
            int r = idx & 15, k = idx >> 4;
            hs[idx] = hnorm[(size_t)(r0 + r) * DD + k0 + k];
        }
        __syncthreads();
        float acc[16];
        #pragma unroll
        for (int r = 0; r < 16; ++r) acc[r] = 0.0f;
        #pragma unroll 4
        for (int k = 0; k < 64; ++k) {
            float wv = We1[(size_t)(k0 + k) * DD + col];
            const float* hrow = hs + k * 16;
            #pragma unroll
            for (int j = 0; j < 4; ++j) {
                float4 h4 = *(const float4*)(hrow + j * 4);
                acc[j * 4 + 0] = fmaf(h4.x, wv, acc[j * 4 + 0]);
                acc[j * 4 + 1] = fmaf(h4.y, wv, acc[j * 4 + 1]);
                acc[j * 4 + 2] = fmaf(h4.z, wv, acc[j * 4 + 2]);
                acc[j * 4 + 3] = fmaf(h4.w, wv, acc[j * 4 + 3]);
            }
        }
        float* o = He + (size_t)((q >> 1) & 15) * 32 * DD;
        #pragma unroll
        for (int r = 0; r < 16; ++r) o[(size_t)(r0 + r) * DD + col] = acc[r];
    }
}

// ---------------- K3: edge kernel (blocks 0..4095) + energy2 (4096..4127)
// Edge path: 4 edges per wave (16384 waves), single-edge pipeline stages with
// one-edge-ahead register double buffering (16 VGPR per stage vs R7's 32) for
// higher occupancy; pair-packed reduction every 2 edges.
__global__ __launch_bounds__(256) void k3_edge_energy2_kernel(
    const unsigned short* __restrict__ P, const int* __restrict__ edge_index,
    const float* __restrict__ evec, const float* __restrict__ edist,
    const float* __restrict__ Wf2, const float* __restrict__ bf2,
    const float* __restrict__ He, const float* __restrict__ be1,
    const float* __restrict__ We2, const float* __restrict__ be2,
    float* __restrict__ out) {
    __shared__ float red[256];
    int t = threadIdx.x;
    int b = blockIdx.x;
    if (b < 4096) {
        float* forces = out + BB;
        int lane = t & 63;
        int wv = b * 4 + (t >> 6);  // 0..16383
        int dbase = lane * 8;
        float wreg[16];
        #pragma unroll
        for (int s = 0; s < 2; ++s) {
            float4 a = *(const float4*)(Wf2 + s * 512 + dbase);
            float4 c = *(const float4*)(Wf2 + s * 512 + dbase + 4);
            wreg[s * 8 + 0] = a.x; wreg[s * 8 + 1] = a.y;
            wreg[s * 8 + 2] = a.z; wreg[s * 8 + 3] = a.w;
            wreg[s * 8 + 4] = c.x; wreg[s * 8 + 5] = c.y;
            wreg[s * 8 + 6] = c.z; wreg[s * 8 + 7] = c.w;
        }
        float bias2 = bf2[0];
        const unsigned short* P1 = P + (size_t)NNODES * DD;

        // hoist the 4 edges' endpoints into SGPRs (wave-uniform)
        int i0v[4], i1v[4];
        #pragma unroll
        for (int j = 0; j < 4; ++j) {
            int e = wv + j * 16384;
            i0v[j] = __builtin_amdgcn_readfirstlane(edge_index[e]);
            i1v[j] = __builtin_amdgcn_readfirstlane(edge_index[EE + e]);
        }

        // stage buffers: [buf][0..1] = p0 seg0/1, [2..3] = p1 seg0/1
        ushortx8 buf[2][4];
        #pragma unroll
        for (int s = 0; s < 2; ++s) {
            buf[0][0 + s] = *(const ushortx8*)(P  + (size_t)i0v[0] * DD + dbase + s * 512);
            buf[0][2 + s] = *(const ushortx8*)(P1 + (size_t)i1v[0] * DD + dbase + s * 512);
        }
        float accs[2];
        #pragma unroll
        for (int j = 0; j < 4; ++j) {
            if (j < 3) {
                ushortx8* nb = buf[(j + 1) & 1];
                #pragma unroll
                for (int s = 0; s < 2; ++s) {
                    nb[0 + s] = *(const ushortx8*)(P  + (size_t)i0v[j + 1] * DD + dbase + s * 512);
                    nb[2 + s] = *(const ushortx8*)(P1 + (size_t)i1v[j + 1] * DD + dbase + s * 512);
                }
            }
            const ushortx8* cb = buf[j & 1];
            float acc = 0.0f;
            #pragma unroll
            for (int s = 0; s < 2; ++s) {
                #pragma unroll
                for (int jj = 0; jj < 8; ++jj) {
                    float hv = bf16_to_f32((unsigned short)cb[s][jj]) +
                               bf16_to_f32((unsigned short)cb[2 + s][jj]);
                    acc = fmaf(gelu_sig(hv), wreg[s * 8 + jj], acc);
                }
            }
            accs[j & 1] = acc;
            if (j & 1) {
                // reduce pair (edge j-1 even, edge j odd)
                float a0 = accs[0], a1 = accs[1];
                a0 += __shfl_xor(a0, 32, 64);
                a1 += __shfl_xor(a1, 32, 64);
                float r = (lane < 32) ? a0 : a1;
                #pragma unroll
                for (int off = 16; off > 0; off >>= 1) r += __shfl_xor(r, off, 64);
                float fm = r + bias2;
                int l5 = lane & 31;
                if (l5 < 3) {
                    int je = (lane < 32) ? (j - 1) : j;
                    int e = wv + je * 16384;
                    int i0 = (lane < 32) ? i0v[j - 1] : i0v[j];
                    float sc = fm / edist[e];
                    atomicAdd(&forces[i0 * 3 + l5], sc * evec[e * 3 + l5]);
                }
            }
        }
        return;
    }
    // energy2: sum 16 partials, gelu, dot We2
    {
        int bb = b - 4096;
        float p = 0.0f;
        #pragma unroll
        for (int j = 0; j < 4; ++j) {
            int c = t * 4 + j;
            float s = 0.0f;
            #pragma unroll
            for (int ks = 0; ks < 16; ++ks)
                s += He[(size_t)ks * 32 * DD + bb * DD + c];
            s += be1[c];
            p += gelu_fast(s) * We2[c];
        }
        red[t] = p; __syncthreads();
        for (int off = 128; off > 0; off >>= 1) {
            if (t < off) red[t] += red[t + off];
            __syncthreads();
        }
        if (t == 0) out[bb] = red[0] + be2[0];
    }
}

extern "C" void kernel_launch(void* const* d_in, const int* in_sizes, int n_in,
                              void* d_out, int out_size, void* d_ws, size_t ws_size,
                              hipStream_t stream) {
    const float* x    = (const float*)d_in[0];
    const int* edge_index = (const int*)d_in[2];
    const float* evec = (const float*)d_in[3];
    const float* edist = (const float*)d_in[4];
    const float* ln_g = (const float*)d_in[6];
    const float* ln_b = (const float*)d_in[7];
    const float* We1  = (const float*)d_in[8];
    const float* be1  = (const float*)d_in[9];
    const float* We2  = (const float*)d_in[10];
    const float* be2  = (const float*)d_in[11];
    const float* Wf1  = (const float*)d_in[12];
    const float* bf1  = (const float*)d_in[13];
    const float* Wf2  = (const float*)d_in[14];
    const float* bf2  = (const float*)d_in[15];

    float* out = (float*)d_out;  // [0:32] energy, [32:32+6144] forces

    // ws layout:
    // [0, 8MB)          : P bf16 [2][2048][1024]
    // [8MB, 10MB+128KB) : hnorm (128 KB) + He (2 MB)
    // [11MB, 15MB)      : nodesB bf16 [2048][1024]
    // [16MB, 20MB)      : Wf1T  bf16 [2][1024][1024]
    char* wsb = (char*)d_ws;
    unsigned short* P      = (unsigned short*)(wsb);
    float* hnorm           = (float*)(wsb + (8u << 20));
    float* He              = (float*)(wsb + (8u << 20) + (128u << 10));
    unsigned short* nodesB = (unsigned short*)(wsb + (11u << 20));
    unsigned short* Wf1T   = (unsigned short*)(wsb + (16u << 20));

    k1_zero_ln_prep_kernel<<<4128, 256, 0, stream>>>(x, ln_g, ln_b, Wf1, hnorm,
                                                     out, nodesB, Wf1T);
    k2_gemm_kernel<<<320, 512, 0, stream>>>(nodesB, Wf1T, bf1, P, hnorm, We1, He);
    k3_edge_energy2_kernel<<<4128, 256, 0, stream>>>(P, edge_index, evec, edist,
                                                     Wf2, bf2, He, be1, We2, be2,
                                                     out);
}

// Round 9
// 151.279 us; speedup vs baseline: 1.3622x; 1.0066x over previous
//
#include <hip/hip_runtime.h>
#include <hip/hip_fp16.h>
#include <math.h>

#define BB 32
#define TT 256
#define DD 1024
#define NNODES 2048
#define EE 65536
#define LN_EPS 1e-5f

typedef _Float16 halfx8 __attribute__((ext_vector_type(8)));
typedef __attribute__((ext_vector_type(4))) float floatx4;

__device__ __forceinline__ float gelu_fast(float x) {
    // tanh-approx gelu: x - x/(1+exp2(x*(2.302118 + 0.102945*x^2)))
    float x2 = x * x;
    float z = x * fmaf(0.10294456f, x2, 2.30211786f);
    float e = __builtin_amdgcn_exp2f(z);
    float r = __builtin_amdgcn_rcpf(1.0f + e);
    return fmaf(-x, r, x);
}

// packed half2 sigmoid-gelu: x / (1 + exp2(-2.4554669 x))
__device__ __forceinline__ __half2 gelu_h2(__half2 x) {
    const __half2 k = __float2half2_rn(-2.4554669f);
    const __half2 one = __float2half2_rn(1.0f);
    __half2 e = h2exp2(__hmul2(x, k));
    return __hmul2(x, h2rcp(__hadd2(e, one)));
}

__device__ __forceinline__ float dot2f(__half2 a, __half2 b, float c) {
#if __has_builtin(__builtin_amdgcn_fdot2)
    typedef _Float16 v2h __attribute__((ext_vector_type(2)));
    return __builtin_amdgcn_fdot2(*(v2h*)&a, *(v2h*)&b, c, false);
#else
    float2 af = __half22float2(a), bf = __half22float2(b);
    return fmaf(af.x, bf.x, fmaf(af.y, bf.y, c));
#endif
}

__device__ __forceinline__ unsigned short f32_to_h16(float f) {
    return __half_as_ushort(__float2half_rn(f));
}

__device__ __forceinline__ void load_lds16(const void* g, void* l) {
    __builtin_amdgcn_global_load_lds(
        (const __attribute__((address_space(1))) void*)g,
        (__attribute__((address_space(3))) void*)l, 16, 0, 0);
}

// ---------------- K1: zero d_out + LayerNorm (blocks 0..31) + prep (32..4127)
__global__ __launch_bounds__(256) void k1_zero_ln_prep_kernel(
    const float* __restrict__ x, const float* __restrict__ g,
    const float* __restrict__ bta, const float* __restrict__ Wf1,
    float* __restrict__ hnorm, float* __restrict__ out,
    unsigned short* __restrict__ nodesH, unsigned short* __restrict__ Wf1T) {
    __shared__ float smem[32 * 33];
    int t = threadIdx.x;
    int b = blockIdx.x;
    if (b < BB) {
        int zi = b * 256 + t;
        if (zi < BB + NNODES * 3) out[zi] = 0.0f;
        float* red = smem;
        const float* row = x + (size_t)b * TT * DD;
        float v[4];
        float s = 0.0f;
        #pragma unroll
        for (int j = 0; j < 4; ++j) { v[j] = row[t + j * 256]; s += v[j]; }
        red[t] = s; __syncthreads();
        for (int off = 128; off > 0; off >>= 1) {
            if (t < off) red[t] += red[t + off];
            __syncthreads();
        }
        float mu = red[0] * (1.0f / DD);
        __syncthreads();
        float sq = 0.0f;
        #pragma unroll
        for (int j = 0; j < 4; ++j) { float d = v[j] - mu; sq += d * d; }
        red[t] = sq; __syncthreads();
        for (int off = 128; off > 0; off >>= 1) {
            if (t < off) red[t] += red[t + off];
            __syncthreads();
        }
        float rstd = rsqrtf(red[0] * (1.0f / DD) + LN_EPS);
        #pragma unroll
        for (int j = 0; j < 4; ++j) {
            int d = t + j * 256;
            hnorm[b * DD + d] = (v[j] - mu) * rstd * g[d] + bta[d];
        }
        return;
    }
    int pb = b - BB;
    if (pb < 2048) {
        int idx4 = (pb * 256 + t) * 4;
        int i = idx4 >> 10;
        int k = idx4 & 1023;
        const float* src = x + ((size_t)(i >> 6) * TT + 1 + (i & 63)) * DD + k;
        float4 v = *(const float4*)src;
        ushort4 o;
        o.x = f32_to_h16(v.x); o.y = f32_to_h16(v.y);
        o.z = f32_to_h16(v.z); o.w = f32_to_h16(v.w);
        *(ushort4*)&nodesH[idx4] = o;
    } else {
        int q = pb - 2048;
        float (*tile)[33] = (float(*)[33])smem;
        int tx = t & 31;
        int ty = t >> 5;
        int n0 = (q & 31) * 32;
        int kg0 = (q >> 5) * 32;
        #pragma unroll
        for (int j = 0; j < 4; ++j) {
            int r = ty * 4 + j;
            tile[r][tx] = Wf1[(size_t)(kg0 + r) * DD + n0 + tx];
        }
        __syncthreads();
        int half = kg0 >> 10;
        int kk0 = kg0 & 1023;
        unsigned short* o = Wf1T + (size_t)half * DD * DD;
        #pragma unroll
        for (int j = 0; j < 4; ++j) {
            int rn = ty * 4 + j;
            o[(size_t)(n0 + rn) * DD + kk0 + tx] = f32_to_h16(tile[tx][rn]);
        }
    }
}

// ---------------- K2: MFMA (f16) pgemm (blocks 0..255, 512 thr = 8 waves) +
//                      energy1 split-K GEMM (blocks 256..319)
__global__ __launch_bounds__(512) void k2_gemm_kernel(
    const unsigned short* __restrict__ nodesH,
    const unsigned short* __restrict__ Wf1T, const float* __restrict__ bf1,
    unsigned short* __restrict__ P, const float* __restrict__ hnorm,
    const float* __restrict__ We1, float* __restrict__ He) {
    __shared__ unsigned short smem[2 * 128 * 64];  // 32 KB
    int t = threadIdx.x;
    int b = blockIdx.x;
    if (b < 256) {
        unsigned short* As = smem;            // [n-row][k] XOR-swizzled chunks
        unsigned short* Bs = smem + 128 * 64; // [i-row][k]
        int w = t >> 6;
        int lane = t & 63;
        int quad = lane >> 4;
        int l16 = lane & 15;
        int wn = (w & 3) * 32;
        int wi = (w >> 2) * 64;
        int n0 = (b & 7) * 128;
        int i0 = ((b >> 3) & 15) * 128;
        int half = b >> 7;

        const unsigned short* Ag = Wf1T + (size_t)half * DD * DD;
        const unsigned short* Bg = nodesH;

        int sr = lane >> 3;
        int sc = (lane & 7) ^ sr;
        size_t aoff[2], boff[2];
        #pragma unroll
        for (int j = 0; j < 2; ++j) {
            int row = w * 16 + j * 8;
            aoff[j] = (size_t)(n0 + row + sr) * DD + sc * 8;
            boff[j] = (size_t)(i0 + row + sr) * DD + sc * 8;
        }

        floatx4 acc[2][4];
        #pragma unroll
        for (int a = 0; a < 2; ++a)
            #pragma unroll
            for (int c = 0; c < 4; ++c) {
                acc[a][c][0] = 0.f; acc[a][c][1] = 0.f;
                acc[a][c][2] = 0.f; acc[a][c][3] = 0.f;
            }

        for (int k0 = 0; k0 < DD; k0 += 64) {
            #pragma unroll
            for (int j = 0; j < 2; ++j) {
                int row = w * 16 + j * 8;
                load_lds16(Ag + aoff[j] + k0, (void*)(As + row * 64));
                load_lds16(Bg + boff[j] + k0, (void*)(Bs + row * 64));
            }
            __syncthreads();
            #pragma unroll
            for (int s = 0; s < 2; ++s) {
                halfx8 af[2], bfr[4];
                #pragma unroll
                for (int f = 0; f < 2; ++f) {
                    int rn = wn + f * 16 + l16;
                    af[f] = *(const halfx8*)&As[rn * 64 + ((((s << 2) | quad) ^ (rn & 7)) << 3)];
                }
                #pragma unroll
                for (int f = 0; f < 4; ++f) {
                    int ri = wi + f * 16 + l16;
                    bfr[f] = *(const halfx8*)&Bs[ri * 64 + ((((s << 2) | quad) ^ (ri & 7)) << 3)];
                }
                #pragma unroll
                for (int fa = 0; fa < 2; ++fa)
                    #pragma unroll
                    for (int fb = 0; fb < 4; ++fb)
                        acc[fa][fb] = __builtin_amdgcn_mfma_f32_16x16x32_f16(
                            af[fa], bfr[fb], acc[fa][fb], 0, 0, 0);
            }
            __syncthreads();
        }

        unsigned short* Pout = P + (size_t)half * NNODES * DD;
        #pragma unroll
        for (int fa = 0; fa < 2; ++fa) {
            int n = n0 + wn + fa * 16 + quad * 4;
            float4 badd = make_float4(0.f, 0.f, 0.f, 0.f);
            if (half == 0) badd = *(const float4*)(bf1 + n);
            #pragma unroll
            for (int fb = 0; fb < 4; ++fb) {
                int i = i0 + wi + fb * 16 + l16;
                floatx4 v = acc[fa][fb];
                ushort4 o;
                o.x = f32_to_h16(v[0] + badd.x);
                o.y = f32_to_h16(v[1] + badd.y);
                o.z = f32_to_h16(v[2] + badd.z);
                o.w = f32_to_h16(v[3] + badd.w);
                *(ushort4*)&Pout[(size_t)i * DD + n] = o;
            }
        }
        return;
    }
    // energy1: He[ks][r0+r][col] = sum_{64k chunk} h[r][k]*We1[k][col]
    {
        int q = b - 256;
        float* hs = (float*)smem;  // [k][r] 64x16
        int col = (q & 1) * 512 + t;
        int k0 = ((q >> 1) & 15) * 64;
        int r0 = (q >> 5) * 16;
        for (int idx = t; idx < 64 * 16; idx += 512) {
            int r = idx & 15, k = idx >> 4;
            hs[idx] = hnorm[(size_t)(r0 + r) * DD + k0 + k];
        }
        __syncthreads();
        float acc[16];
        #pragma unroll
        for (int r = 0; r < 16; ++r) acc[r] = 0.0f;
        #pragma unroll 4
        for (int k = 0; k < 64; ++k) {
            float wv = We1[(size_t)(k0 + k) * DD + col];
            const float* hrow = hs + k * 16;
            #pragma unroll
            for (int j = 0; j < 4; ++j) {
                float4 h4 = *(const float4*)(hrow + j * 4);
                acc[j * 4 + 0] = fmaf(h4.x, wv, acc[j * 4 + 0]);
                acc[j * 4 + 1] = fmaf(h4.y, wv, acc[j * 4 + 1]);
                acc[j * 4 + 2] = fmaf(h4.z, wv, acc[j * 4 + 2]);
                acc[j * 4 + 3] = fmaf(h4.w, wv, acc[j * 4 + 3]);
            }
        }
        float* o = He + (size_t)((q >> 1) & 15) * 32 * DD;
        #pragma unroll
        for (int r = 0; r < 16; ++r) o[(size_t)(r0 + r) * DD + col] = acc[r];
    }
}

// ---------------- K3: edge kernel (blocks 0..4095) + energy2 (4096..4127)
// Edge math in packed half2 (hadd2/hmul2/h2exp2/h2rcp) with v_dot2_f32_f16
// accumulation: 5 full-rate + 4 transcendental ops per element-pair (vs 12+4
// in the f32 path). 4 edges per wave, one-edge-ahead register double buffer.
__global__ __launch_bounds__(256) void k3_edge_energy2_kernel(
    const unsigned short* __restrict__ P, const int* __restrict__ edge_index,
    const float* __restrict__ evec, const float* __restrict__ edist,
    const float* __restrict__ Wf2, const float* __restrict__ bf2,
    const float* __restrict__ He, const float* __restrict__ be1,
    const float* __restrict__ We2, const float* __restrict__ be2,
    float* __restrict__ out) {
    __shared__ float red[256];
    int t = threadIdx.x;
    int b = blockIdx.x;
    if (b < 4096) {
        float* forces = out + BB;
        int lane = t & 63;
        int wv = b * 4 + (t >> 6);  // 0..16383
        int dbase = lane * 8;
        // Wf2 lane slice as 8 half2 (16 elements: 2 segments x 8)
        __half2 wh[8];
        #pragma unroll
        for (int s = 0; s < 2; ++s) {
            float4 a = *(const float4*)(Wf2 + s * 512 + dbase);
            float4 c = *(const float4*)(Wf2 + s * 512 + dbase + 4);
            wh[s * 4 + 0] = __floats2half2_rn(a.x, a.y);
            wh[s * 4 + 1] = __floats2half2_rn(a.z, a.w);
            wh[s * 4 + 2] = __floats2half2_rn(c.x, c.y);
            wh[s * 4 + 3] = __floats2half2_rn(c.z, c.w);
        }
        float bias2 = bf2[0];
        const unsigned short* P1 = P + (size_t)NNODES * DD;

        int i0v[4], i1v[4];
        #pragma unroll
        for (int j = 0; j < 4; ++j) {
            int e = wv + j * 16384;
            i0v[j] = __builtin_amdgcn_readfirstlane(edge_index[e]);
            i1v[j] = __builtin_amdgcn_readfirstlane(edge_index[EE + e]);
        }

        // stage buffers: [buf][0..1] = p0 seg0/1, [2..3] = p1 seg0/1 (16B each)
        float4 buf[2][4];
        #pragma unroll
        for (int s = 0; s < 2; ++s) {
            buf[0][0 + s] = *(const float4*)(P  + (size_t)i0v[0] * DD + dbase + s * 512);
            buf[0][2 + s] = *(const float4*)(P1 + (size_t)i1v[0] * DD + dbase + s * 512);
        }
        float accs[2];
        #pragma unroll
        for (int j = 0; j < 4; ++j) {
            if (j < 3) {
                float4* nb = buf[(j + 1) & 1];
                #pragma unroll
                for (int s = 0; s < 2; ++s) {
                    nb[0 + s] = *(const float4*)(P  + (size_t)i0v[j + 1] * DD + dbase + s * 512);
                    nb[2 + s] = *(const float4*)(P1 + (size_t)i1v[j + 1] * DD + dbase + s * 512);
                }
            }
            const float4* cb = buf[j & 1];
            float acc = 0.0f;
            #pragma unroll
            for (int s = 0; s < 2; ++s) {
                const __half2* h0 = (const __half2*)&cb[s];
                const __half2* h1 = (const __half2*)&cb[2 + s];
                #pragma unroll
                for (int jj = 0; jj < 4; ++jj) {
                    __half2 hv = __hadd2(h0[jj], h1[jj]);
                    acc = dot2f(gelu_h2(hv), wh[s * 4 + jj], acc);
                }
            }
            accs[j & 1] = acc;
            if (j & 1) {
                float a0 = accs[0], a1 = accs[1];
                a0 += __shfl_xor(a0, 32, 64);
                a1 += __shfl_xor(a1, 32, 64);
                float r = (lane < 32) ? a0 : a1;
                #pragma unroll
                for (int off = 16; off > 0; off >>= 1) r += __shfl_xor(r, off, 64);
                float fm = r + bias2;
                int l5 = lane & 31;
                if (l5 < 3) {
                    int je = (lane < 32) ? (j - 1) : j;
                    int e = wv + je * 16384;
                    int i0 = (lane < 32) ? i0v[j - 1] : i0v[j];
                    float sc = fm / edist[e];
                    atomicAdd(&forces[i0 * 3 + l5], sc * evec[e * 3 + l5]);
                }
            }
        }
        return;
    }
    // energy2: sum 16 partials, gelu, dot We2 (fp32 path)
    {
        int bb = b - 4096;
        float p = 0.0f;
        #pragma unroll
        for (int j = 0; j < 4; ++j) {
            int c = t * 4 + j;
            float s = 0.0f;
            #pragma unroll
            for (int ks = 0; ks < 16; ++ks)
                s += He[(size_t)ks * 32 * DD + bb * DD + c];
            s += be1[c];
            p += gelu_fast(s) * We2[c];
        }
        red[t] = p; __syncthreads();
        for (int off = 128; off > 0; off >>= 1) {
            if (t < off) red[t] += red[t + off];
            __syncthreads();
        }
        if (t == 0) out[bb] = red[0] + be2[0];
    }
}

extern "C" void kernel_launch(void* const* d_in, const int* in_sizes, int n_in,
                              void* d_out, int out_size, void* d_ws, size_t ws_size,
                              hipStream_t stream) {
    const float* x    = (const float*)d_in[0];
    const int* edge_index = (const int*)d_in[2];
    const float* evec = (const float*)d_in[3];
    const float* edist = (const float*)d_in[4];
    const float* ln_g = (const float*)d_in[6];
    const float* ln_b = (const float*)d_in[7];
    const float* We1  = (const float*)d_in[8];
    const float* be1  = (const float*)d_in[9];
    const float* We2  = (const float*)d_in[10];
    const float* be2  = (const float*)d_in[11];
    const float* Wf1  = (const float*)d_in[12];
    const float* bf1  = (const float*)d_in[13];
    const float* Wf2  = (const float*)d_in[14];
    const float* bf2  = (const float*)d_in[15];

    float* out = (float*)d_out;  // [0:32] energy, [32:32+6144] forces

    // ws layout:
    // [0, 8MB)          : P fp16 [2][2048][1024]
    // [8MB, 10MB+128KB) : hnorm (128 KB) + He (2 MB)
    // [11MB, 15MB)      : nodesH fp16 [2048][1024]
    // [16MB, 20MB)      : Wf1T  fp16 [2][1024][1024]
    char* wsb = (char*)d_ws;
    unsigned short* P      = (unsigned short*)(wsb);
    float* hnorm           = (float*)(wsb + (8u << 20));
    float* He              = (float*)(wsb + (8u << 20) + (128u << 10));
    unsigned short* nodesH = (unsigned short*)(wsb + (11u << 20));
    unsigned short* Wf1T   = (unsigned short*)(wsb + (16u << 20));

    k1_zero_ln_prep_kernel<<<4128, 256, 0, stream>>>(x, ln_g, ln_b, Wf1, hnorm,
                                                     out, nodesH, Wf1T);
    k2_gemm_kernel<<<320, 512, 0, stream>>>(nodesH, Wf1T, bf1, P, hnorm, We1, He);
    k3_edge_energy2_kernel<<<4128, 256, 0, stream>>>(P, edge_index, evec, edist,
                                                     Wf2, bf2, He, be1, We2, be2,
                                                     out);
}